// Round 14
// baseline (979.768 us; speedup 1.0000x reference)
//
#include <hip/hip_runtime.h>
#include <cstdint>
#include <cstddef>

static constexpr int Bc  = 32;
static constexpr int Nc  = 1024;
static constexpr int Kc  = 20;
static constexpr int Mc  = 8;
static constexpr int BNc = Bc * Nc;          // 32768
static constexpr int BNKc = BNc * Kc;        // 655360
static constexpr int NSLOT = 512;            // bnslots stride

typedef __attribute__((ext_vector_type(4))) float f32x4;
typedef _Float16 f16x8 __attribute__((ext_vector_type(8)));

__device__ inline short f2h(float v) { _Float16 h = (_Float16)v; return __builtin_bit_cast(short, h); }
__device__ inline float h2f(short s) { return (float)__builtin_bit_cast(_Float16, s); }

// ---------------- zero kernel ----------------
__global__ void zero_kernel(float* p, int n) {
  int gid = blockIdx.x * blockDim.x + threadIdx.x;
  if (gid < n) p[gid] = 0.f;
}

// ---------------- KNN: register-resident selection, 4 waves/block, 1 point/wave ----------------
__global__ __launch_bounds__(256) void knn_kernel(const float* __restrict__ x,
                                                  int* __restrict__ idxout) {
  int wv = threadIdx.x >> 6;
  int bn = blockIdx.x * 4 + wv;
  int b = bn >> 10, n = bn & (Nc - 1);
  int lane = threadIdx.x & 63;
  const float* xb = x + (size_t)b * 3 * Nc;
  float cx = xb[n], cy = xb[Nc + n], cz = xb[2 * Nc + n];
  float sqc = cx * cx + cy * cy + cz * cz;
  float d[16];
#pragma unroll
  for (int j = 0; j < 16; j++) {
    int m2 = j * 64 + lane;
    float xm = xb[m2], ym = xb[Nc + m2], zm = xb[2 * Nc + m2];
    d[j] = 2.f * (cx * xm + cy * ym + cz * zm) - sqc - (xm * xm + ym * ym + zm * zm);
  }
  int* out = idxout + (size_t)bn * Kc;
  for (int kk = 0; kk < Kc; kk++) {
    float bd = d[0]; int bj = 0;
#pragma unroll
    for (int j = 1; j < 16; j++)
      if (d[j] > bd) { bd = d[j]; bj = j; }
    int bm = bj * 64 + lane;
#pragma unroll
    for (int off = 32; off; off >>= 1) {
      float od = __shfl_down(bd, off);
      int   om = __shfl_down(bm, off);
      if (od > bd || (od == bd && om < bm)) { bd = od; bm = om; }
    }
    bm = __shfl(bm, 0);
    if (lane == 0) out[kk] = bm;
    int bmj = bm >> 6;
    bool mine = (bm & 63) == lane;
#pragma unroll
    for (int j = 0; j < 16; j++)
      if (mine && j == bmj) d[j] = -3e38f;
  }
}

// ---------------- x transpose: (B,3,N) -> (B,N,3) ----------------
__global__ __launch_bounds__(256) void xt_kernel(const float* __restrict__ x,
                                                 float* __restrict__ xT) {
  int gid = blockIdx.x * blockDim.x + threadIdx.x;   // over B*N*3
  int c = gid % 3;
  int bn = gid / 3;
  int b = bn >> 10, n = bn & (Nc - 1);
  xT[gid] = x[((size_t)b * 3 + c) * Nc + n];
}

// xyz recompute helper
__device__ inline void xyz_at(const float* __restrict__ xT, const int* __restrict__ idx,
                              int e, float v[6]) {
  int bn = e / Kc;
  int b = bn >> 10;
  int nb = idx[e];
  const float* pc = xT + (size_t)bn * 3;
  const float* pn = xT + ((size_t)(b << 10) + nb) * 3;
#pragma unroll
  for (int c = 0; c < 3; c++) { float nv = pn[c]; v[c] = nv - pc[c]; v[3 + c] = nv; }
}

// ---------------- xyz statistics ----------------
__global__ __launch_bounds__(256) void xyz_stats_kernel(const float* __restrict__ xT,
                                                        const int* __restrict__ idx,
                                                        float* __restrict__ accum) {
  __shared__ float sPart[4 * 42];
  int tid = threadIdx.x;
  int gid = blockIdx.x * 256 + tid;
  float a[42];
#pragma unroll
  for (int t = 0; t < 42; t++) a[t] = 0.f;
  for (int i = 0; i < 8; i++) {
    float v[6];
    xyz_at(xT, idx, gid + i * 81920, v);
#pragma unroll
    for (int c = 0; c < 6; c++) a[c] += v[c];
    int t = 6;
#pragma unroll
    for (int c = 0; c < 6; c++)
#pragma unroll
      for (int d = 0; d < 6; d++) a[t++] += v[c] * v[d];
  }
  int lane = tid & 63, wid = tid >> 6;
#pragma unroll
  for (int t = 0; t < 42; t++) {
    float v = a[t];
#pragma unroll
    for (int off = 32; off; off >>= 1) v += __shfl_down(v, off);
    if (lane == 0) sPart[wid * 42 + t] = v;
  }
  __syncthreads();
  if (tid < 42) {
    float s = sPart[tid] + sPart[42 + tid] + sPart[84 + tid] + sPart[126 + tid];
    atomicAdd(&accum[tid], s);
  }
}

// ---------------- scorenet bn stats (all 4 layers) ----------------
__global__ void snstats_kernel(const float* __restrict__ accum,
                               const float* __restrict__ w1a, const float* __restrict__ w1b,
                               const float* __restrict__ w1c, const float* __restrict__ w1d,
                               float* __restrict__ snstats) {
  int t = threadIdx.x;       // 0..63
  int l = t >> 4, j = t & 15;
  const float* w1 = (l == 0) ? w1a : (l == 1) ? w1b : (l == 2) ? w1c : w1d;
  const float invc = 1.f / (float)BNKc;
  float wj[6];
  float mu = 0.f;
#pragma unroll
  for (int c = 0; c < 6; c++) { wj[c] = w1[c * 16 + j]; mu += accum[c] * invc * wj[c]; }
  float e2 = 0.f;
#pragma unroll
  for (int c = 0; c < 6; c++)
#pragma unroll
    for (int d = 0; d < 6; d++) e2 += wj[c] * wj[d] * (accum[6 + c * 6 + d] * invc);
  float var = e2 - mu * mu;
  snstats[t * 2] = mu;
  snstats[t * 2 + 1] = rsqrtf(var + 1e-5f);
}

// ---------------- score kernel (standalone, fully parallel over BNK) ----------------
__global__ __launch_bounds__(256) void score_kernel(const float* __restrict__ xT,
                                                    const int* __restrict__ idx,
                                                    const float* __restrict__ w1,
                                                    const float* __restrict__ w2,
                                                    const float* __restrict__ bias,
                                                    const float* __restrict__ snst,
                                                    float* __restrict__ score) {
  __shared__ float sW1[96], sW2[128], sB[8], sMu[16], sRs[16];
  int tid = threadIdx.x;
  if (tid < 96) sW1[tid] = w1[tid];
  else if (tid < 224) sW2[tid - 96] = w2[tid - 96];
  else if (tid < 232) sB[tid - 224] = bias[tid - 224];
  else if (tid < 248) { sMu[tid - 232] = snst[(tid - 232) * 2]; sRs[tid - 232] = snst[(tid - 232) * 2 + 1]; }
  __syncthreads();
  int e = blockIdx.x * 256 + tid;    // exact BNK
  float v[6];
  xyz_at(xT, idx, e, v);
  float h[16];
#pragma unroll
  for (int j = 0; j < 16; j++) {
    float a = 0.f;
#pragma unroll
    for (int c = 0; c < 6; c++) a += v[c] * sW1[c * 16 + j];
    a = (a - sMu[j]) * sRs[j];
    h[j] = a > 0.f ? a : 0.f;
  }
  float s[8];
  float mx = -3e38f;
#pragma unroll
  for (int m = 0; m < 8; m++) {
    float a = sB[m];
#pragma unroll
    for (int j = 0; j < 16; j++) a += h[j] * sW2[j * 8 + m];
    s[m] = a;
    mx = fmaxf(mx, a);
  }
  float sum = 0.f;
#pragma unroll
  for (int m = 0; m < 8; m++) { s[m] = expf(s[m] - mx); sum += s[m]; }
  float inv = 1.f / sum;
#pragma unroll
  for (int m = 0; m < 8; m++) score[(size_t)e * 8 + m] = s[m] * inv + 0.5f;
}

// ---------------- L1 fused paconv (fp32 compute, fp32 out, no atomics) ----------------
template <int C, int Co, int MH>
__global__ __launch_bounds__(256) void paconv_kernel(
    const float* __restrict__ feat, int fstride,
    const float* __restrict__ ker,
    const float* __restrict__ score,
    const int* __restrict__ idx,
    float* __restrict__ outp, int ostride) {
  constexpr int PT = 8;
  constexpr int MS = Mc / MH;
  __shared__ float sX[PT][2 * MH * C];
  __shared__ float sSc[PT * Kc * Mc];
  __shared__ int sIdx[PT * Kc];
  __shared__ float sFc[PT][C];
  __shared__ float sSum[PT][Mc];

  int tid = threadIdx.x;
  int pbase = blockIdx.x * PT;
  int bN = pbase & ~(Nc - 1);

  for (int e = tid; e < PT * Kc; e += 256) sIdx[e] = idx[(size_t)pbase * Kc + e];
  for (int e = tid; e < PT * Kc * Mc; e += 256) sSc[e] = score[(size_t)pbase * Kc * Mc + e];
  for (int e = tid; e < PT * C; e += 256) {
    int p = e / C, c = e - p * C;
    sFc[p][c] = feat[(size_t)(pbase + p) * fstride + c];
  }
  __syncthreads();
  for (int e = tid; e < PT * Mc; e += 256) {
    int p = e >> 3, m = e & 7;
    float s = 0.f;
#pragma unroll
    for (int k = 0; k < Kc; k++) s += sSc[p * Kc * Mc + k * Mc + m];
    sSum[p][m] = s;
  }
  __syncthreads();

  constexpr int OG = Co;
  constexpr int PG = 256 / OG;
  constexpr int PPT = PT / PG;
  int o = tid % OG;
  int pg = tid / OG;
  float acc[PPT];
#pragma unroll
  for (int i = 0; i < PPT; i++) acc[i] = 0.f;

  for (int ms = 0; ms < MS; ms++) {
    int mb = ms * MH;
    for (int e = tid; e < PT * C; e += 256) {
      int p = e / C, c = e - p * C;
      float t[MH];
#pragma unroll
      for (int mm = 0; mm < MH; mm++) t[mm] = 0.f;
      const float* sc = &sSc[p * Kc * Mc + mb];
      for (int k = 0; k < Kc; k++) {
        float v = feat[(size_t)(bN + sIdx[p * Kc + k]) * fstride + c];
#pragma unroll
        for (int mm = 0; mm < MH; mm++) t[mm] += sc[k * Mc + mm] * v;
      }
      float fc = sFc[p][c];
#pragma unroll
      for (int mm = 0; mm < MH; mm++) {
        sX[p][mm * C + c] = t[mm] - sSum[p][mb + mm] * fc;
        sX[p][MH * C + mm * C + c] = t[mm];
      }
    }
    __syncthreads();
#pragma unroll
    for (int mm = 0; mm < MH; mm++) {
      int m = mb + mm;
      const float* kerm = ker + (size_t)m * Co + o;
      for (int c = 0; c < C; c++) {
        float wA = kerm[(size_t)c * (Mc * Co)];
        float wB = kerm[(size_t)(C + c) * (Mc * Co)];
        int r = mm * C + c;
#pragma unroll
        for (int i = 0; i < PPT; i++) {
          int p = pg * PPT + i;
          acc[i] += sX[p][r] * wA;
          acc[i] += sX[p][MH * C + r] * wB;
        }
      }
    }
    __syncthreads();
  }

#pragma unroll
  for (int i = 0; i < PPT; i++) {
    int p = pg * PPT + i;
    outp[(size_t)(pbase + p) * ostride + o] = acc[i];
  }
}

// ---------------- gather: build T (rows x M*C) fp16 + per-point sum (8) fp16 ----------------
template <int C>
__global__ __launch_bounds__(256) void gather_kernel(
    const short* __restrict__ pb, int coff,
    const float* __restrict__ score,
    const int* __restrict__ idx,
    short* __restrict__ T, short* __restrict__ sumb) {
  constexpr int PT = 256 / C;
  constexpr int KH = Mc * C;
  __shared__ float sSc[PT][Kc][Mc];
  __shared__ int   sIdx[PT][Kc];
  int tid = threadIdx.x;
  int pbase = blockIdx.x * PT;
  int bbase = pbase & ~(Nc - 1);
  for (int e = tid; e < PT * Kc * Mc; e += 256) (&sSc[0][0][0])[e] = score[(size_t)pbase * Kc * Mc + e];
  for (int e = tid; e < PT * Kc; e += 256) (&sIdx[0][0])[e] = idx[(size_t)pbase * Kc + e];
  __syncthreads();
  if (tid < PT * Mc) {
    int p = tid >> 3, m = tid & 7;
    float s = 0.f;
#pragma unroll
    for (int k = 0; k < Kc; k++) s += sSc[p][k][m];
    sumb[(size_t)(pbase + p) * 8 + m] = f2h(s);
  }
  int p = tid / C, c = tid - p * C;
  float t[Mc];
#pragma unroll
  for (int m = 0; m < Mc; m++) t[m] = 0.f;
  for (int k = 0; k < Kc; k++) {
    float v = h2f(pb[(size_t)(bbase + sIdx[p][k]) * 512 + coff + c]);
#pragma unroll
    for (int m = 0; m < Mc; m++) t[m] += sSc[p][k][m] * v;
  }
  short* rowp = T + (size_t)(pbase + p) * KH;
#pragma unroll
  for (int m = 0; m < Mc; m++) rowp[m * C + c] = f2h(t[m]);
}

// ---------------- kernel-matrix convert (rank1 form): B' = [Wa+Wb ; -Wa], (Co x 2KH) fp16 ----------------
__global__ __launch_bounds__(256) void kerconv_r1_kernel(const float* __restrict__ ker,
                                                         short* __restrict__ Bt,
                                                         int C, int Co, int total) {
  int gid = blockIdx.x * 256 + threadIdx.x;
  if (gid >= total) return;
  int KH = Mc * C;
  int K2 = 2 * KH;
  int o = gid / K2, r = gid - o * K2;
  float v;
  if (r < KH) {
    int m = r / C, c = r - m * C;
    v = ker[(size_t)c * (Mc * Co) + m * Co + o] + ker[(size_t)(C + c) * (Mc * Co) + m * Co + o];
  } else {
    int r2 = r - KH;
    int m = r2 / C, c = r2 - m * C;
    v = -ker[(size_t)c * (Mc * Co) + m * Co + o];
  }
  Bt[gid] = f2h(v);
}

// conv5 weight convert: W(512,1024) fp32 -> Wt(1024,512) fp16
__global__ __launch_bounds__(256) void w5conv_kernel(const float* __restrict__ W,
                                                     short* __restrict__ Wt) {
  int gid = blockIdx.x * 256 + threadIdx.x;   // 524288 exact
  int o = gid >> 9, k = gid & 511;
  Wt[gid] = f2h(W[(size_t)k * 1024 + o]);
}

// ---------------- plain fp16 MFMA GEMM + fused bn-stats epilogue (conv5) ----------------
template <int BM, int BN, bool OUT_HALF>
__global__ __launch_bounds__(256) void gemm_kernel(
    const short* __restrict__ A,
    const short* __restrict__ Bt,
    int K,
    void* __restrict__ Cout, int ldc,
    float* __restrict__ bnslots) {
  constexpr int BK = 64;
  constexpr int FN = BN / 32;
  constexpr int FMW = BM / 32;
  __shared__ short sA[BM * BK];
  __shared__ short sB[BN * BK];
  int tid = threadIdx.x;
  int lane = tid & 63, wv = tid >> 6;
  int wrow = (wv & 1) * (BM / 2);
  int wcol = (wv >> 1) * (BN / 2);
  int bm0 = blockIdx.x * BM;
  int bn0 = blockIdx.y * BN;
  int r15 = lane & 15, quad = lane >> 4;
  int swz = r15 & 7;

  f32x4 acc[FMW][FN];
#pragma unroll
  for (int fm = 0; fm < FMW; fm++)
#pragma unroll
    for (int fn = 0; fn < FN; fn++) acc[fm][fn] = (f32x4){0.f, 0.f, 0.f, 0.f};

  for (int k0 = 0; k0 < K; k0 += BK) {
#pragma unroll
    for (int i = 0; i < (BM * BK / 8) / 256; i++) {
      int cb = i * 256 + wv * 64;
      int chunk = cb + lane;
      int row = chunk >> 3, kc = (chunk & 7) ^ (row & 7);
      const short* g = A + (size_t)(bm0 + row) * K + k0 + kc * 8;
      __builtin_amdgcn_global_load_lds((const __attribute__((address_space(1))) void*)g,
                                       (__attribute__((address_space(3))) void*)&sA[cb * 8],
                                       16, 0, 0);
    }
#pragma unroll
    for (int i = 0; i < (BN * BK / 8) / 256; i++) {
      int cb = i * 256 + wv * 64;
      int chunk = cb + lane;
      int row = chunk >> 3, kc = (chunk & 7) ^ (row & 7);
      const short* g = Bt + (size_t)(bn0 + row) * K + k0 + kc * 8;
      __builtin_amdgcn_global_load_lds((const __attribute__((address_space(1))) void*)g,
                                       (__attribute__((address_space(3))) void*)&sB[cb * 8],
                                       16, 0, 0);
    }
    __syncthreads();
#pragma unroll
    for (int kk = 0; kk < BK; kk += 32) {
      f16x8 af[FMW], bf[FN];
      int ccol = (kk >> 3) + quad;
#pragma unroll
      for (int fm = 0; fm < FMW; fm++)
        af[fm] = *(const f16x8*)&sA[(wrow + fm * 16 + r15) * BK + ((ccol ^ swz) * 8)];
#pragma unroll
      for (int fn = 0; fn < FN; fn++)
        bf[fn] = *(const f16x8*)&sB[(wcol + fn * 16 + r15) * BK + ((ccol ^ swz) * 8)];
#pragma unroll
      for (int fm = 0; fm < FMW; fm++)
#pragma unroll
        for (int fn = 0; fn < FN; fn++)
          acc[fm][fn] = __builtin_amdgcn_mfma_f32_16x16x32_f16(af[fm], bf[fn], acc[fm][fn], 0, 0, 0);
    }
    __syncthreads();
  }

  float* sred = (float*)sA;   // 4*BN floats; safe after final barrier
#pragma unroll
  for (int fn = 0; fn < FN; fn++) {
    int col = bn0 + wcol + fn * 16 + r15;
    float ps = 0.f, pq = 0.f;
#pragma unroll
    for (int fm = 0; fm < FMW; fm++) {
      int rowb = bm0 + wrow + fm * 16 + quad * 4;
#pragma unroll
      for (int r = 0; r < 4; r++) {
        float v = acc[fm][fn][r];
        if constexpr (OUT_HALF) ((short*)Cout)[(size_t)(rowb + r) * ldc + col] = f2h(v);
        else                    ((float*)Cout)[(size_t)(rowb + r) * ldc + col] = v;
        ps += v; pq += v * v;
      }
    }
    ps += __shfl_xor(ps, 16); ps += __shfl_xor(ps, 32);
    pq += __shfl_xor(pq, 16); pq += __shfl_xor(pq, 32);
    if (quad == 0) {
      int cl = wcol + fn * 16 + r15;
      sred[(wv & 1) * BN + cl] = ps;
      sred[2 * BN + (wv & 1) * BN + cl] = pq;
    }
  }
  __syncthreads();
  if (tid < BN) {
    float ps = sred[tid] + sred[BN + tid];
    float pq = sred[2 * BN + tid] + sred[3 * BN + tid];
    int col = bn0 + tid;
    bnslots[((size_t)col * NSLOT + blockIdx.x) * 2 + 0] = ps;
    bnslots[((size_t)col * NSLOT + blockIdx.x) * 2 + 1] = pq;
  }
}

// ---------------- rank-1 fp16 MFMA GEMM (L2/L3/L4) + fused bn-stats epilogue ----------------
template <int BM, int BN, int C>
__global__ __launch_bounds__(256) void gemm_r1_kernel(
    const short* __restrict__ T,
    const short* __restrict__ Bt,
    const short* __restrict__ pb, int coff,
    const short* __restrict__ sumb,
    float* __restrict__ Cout, int ldc,
    float* __restrict__ bnslots) {
  constexpr int BK = 64;
  constexpr int KH = Mc * C;
  constexpr int K2 = 2 * KH;
  constexpr int FN = BN / 32;
  constexpr int FMW = BM / 32;
  __shared__ short sA[BM * BK];
  __shared__ short sB[BN * BK];
  __shared__ short sFc[BM * C];
  __shared__ short sSm[BM * 8];
  int tid = threadIdx.x;
  int lane = tid & 63, wv = tid >> 6;
  int wrow = (wv & 1) * (BM / 2);
  int wcol = (wv >> 1) * (BN / 2);
  int bm0 = blockIdx.x * BM;
  int bn0 = blockIdx.y * BN;
  int r15 = lane & 15, quad = lane >> 4;
  int swz = r15 & 7;

  for (int e = tid; e < BM * C; e += 256) {
    int p = e / C, c = e - p * C;
    sFc[e] = pb[(size_t)(bm0 + p) * 512 + coff + c];
  }
  for (int e = tid; e < BM * 8; e += 256) sSm[e] = sumb[(size_t)bm0 * 8 + e];

  f32x4 acc[FMW][FN];
#pragma unroll
  for (int fm = 0; fm < FMW; fm++)
#pragma unroll
    for (int fn = 0; fn < FN; fn++) acc[fm][fn] = (f32x4){0.f, 0.f, 0.f, 0.f};
  __syncthreads();

  for (int k0 = 0; k0 < K2; k0 += BK) {
    if (k0 < KH) {
#pragma unroll
      for (int i = 0; i < (BM * BK / 8) / 256; i++) {
        int cb = i * 256 + wv * 64;
        int chunk = cb + lane;
        int row = chunk >> 3, kc = (chunk & 7) ^ (row & 7);
        const short* g = T + (size_t)(bm0 + row) * KH + k0 + kc * 8;
        __builtin_amdgcn_global_load_lds((const __attribute__((address_space(1))) void*)g,
                                         (__attribute__((address_space(3))) void*)&sA[cb * 8],
                                         16, 0, 0);
      }
    } else {
#pragma unroll
      for (int i = 0; i < (BM * BK / 8) / 256; i++) {
        int cb = i * 256 + wv * 64;
        int chunk = cb + lane;
        int row = chunk >> 3, kc = (chunk & 7) ^ (row & 7);
        int kb = (k0 - KH) + kc * 8;
        int m = kb / C, c = kb - m * C;      // constexpr C -> shifts
        _Float16 sm = __builtin_bit_cast(_Float16, sSm[row * 8 + m]);
        f16x8 fcv = *(const f16x8*)&sFc[row * C + c];
        f16x8 val;
#pragma unroll
        for (int j = 0; j < 8; j++) val[j] = sm * fcv[j];
        *(f16x8*)&sA[chunk * 8] = val;
      }
    }
#pragma unroll
    for (int i = 0; i < (BN * BK / 8) / 256; i++) {
      int cb = i * 256 + wv * 64;
      int chunk = cb + lane;
      int row = chunk >> 3, kc = (chunk & 7) ^ (row & 7);
      const short* g = Bt + (size_t)(bn0 + row) * K2 + k0 + kc * 8;
      __builtin_amdgcn_global_load_lds((const __attribute__((address_space(1))) void*)g,
                                       (__attribute__((address_space(3))) void*)&sB[cb * 8],
                                       16, 0, 0);
    }
    __syncthreads();
#pragma unroll
    for (int kk = 0; kk < BK; kk += 32) {
      f16x8 af[FMW], bf[FN];
      int ccol = (kk >> 3) + quad;
#pragma unroll
      for (int fm = 0; fm < FMW; fm++)
        af[fm] = *(const f16x8*)&sA[(wrow + fm * 16 + r15) * BK + ((ccol ^ swz) * 8)];
#pragma unroll
      for (int fn = 0; fn < FN; fn++)
        bf[fn] = *(const f16x8*)&sB[(wcol + fn * 16 + r15) * BK + ((ccol ^ swz) * 8)];
#pragma unroll
      for (int fm = 0; fm < FMW; fm++)
#pragma unroll
        for (int fn = 0; fn < FN; fn++)
          acc[fm][fn] = __builtin_amdgcn_mfma_f32_16x16x32_f16(af[fm], bf[fn], acc[fm][fn], 0, 0, 0);
    }
    __syncthreads();
  }

  float* sred = (float*)sA;
#pragma unroll
  for (int fn = 0; fn < FN; fn++) {
    int col = bn0 + wcol + fn * 16 + r15;
    float ps = 0.f, pq = 0.f;
#pragma unroll
    for (int fm = 0; fm < FMW; fm++) {
      int rowb = bm0 + wrow + fm * 16 + quad * 4;
#pragma unroll
      for (int r = 0; r < 4; r++) {
        float v = acc[fm][fn][r];
        Cout[(size_t)(rowb + r) * ldc + col] = v;
        ps += v; pq += v * v;
      }
    }
    ps += __shfl_xor(ps, 16); ps += __shfl_xor(ps, 32);
    pq += __shfl_xor(pq, 16); pq += __shfl_xor(pq, 32);
    if (quad == 0) {
      int cl = wcol + fn * 16 + r15;
      sred[(wv & 1) * BN + cl] = ps;
      sred[2 * BN + (wv & 1) * BN + cl] = pq;
    }
  }
  __syncthreads();
  if (tid < BN) {
    float ps = sred[tid] + sred[BN + tid];
    float pq = sred[2 * BN + tid] + sred[3 * BN + tid];
    int col = bn0 + tid;
    bnslots[((size_t)col * NSLOT + blockIdx.x) * 2 + 0] = ps;
    bnslots[((size_t)col * NSLOT + blockIdx.x) * 2 + 1] = pq;
  }
}

// ---------------- bn stats reduction (L1 only) ----------------
template <bool IS_HALF>
__global__ __launch_bounds__(256) void bnstats_kernel(const void* __restrict__ pre,
                                                      int Co,
                                                      float* __restrict__ bnslots) {
  __shared__ float sS[4][64], sQ[4][64];
  int tid = threadIdx.x;
  int c = tid & 63, tg = tid >> 6;
  int ch = blockIdx.x * 64 + c;
  int row0 = blockIdx.y * 1024 + tg * 256;
  float s = 0.f, q = 0.f;
  if constexpr (IS_HALF) {
    const short* p = (const short*)pre + (size_t)row0 * Co + ch;
#pragma unroll 4
    for (int r = 0; r < 256; r++) {
      float v = h2f(p[(size_t)r * Co]);
      s += v; q += v * v;
    }
  } else {
    const float* p = (const float*)pre + (size_t)row0 * Co + ch;
#pragma unroll 4
    for (int r = 0; r < 256; r++) {
      float v = p[(size_t)r * Co];
      s += v; q += v * v;
    }
  }
  sS[tg][c] = s; sQ[tg][c] = q;
  __syncthreads();
  if (tid < 64) {
    float ts = sS[0][tid] + sS[1][tid] + sS[2][tid] + sS[3][tid];
    float tq = sQ[0][tid] + sQ[1][tid] + sQ[2][tid] + sQ[3][tid];
    int chh = blockIdx.x * 64 + tid;
    bnslots[((size_t)chh * NSLOT + blockIdx.y) * 2 + 0] = ts;
    bnslots[((size_t)chh * NSLOT + blockIdx.y) * 2 + 1] = tq;
  }
}

// ---------------- bn finalize (sums nslots valid slots) ----------------
__global__ void bnfinalize_kernel(const float* __restrict__ slots,
                                  float* __restrict__ bnmr, int Co, int nslots) {
  int ch = blockIdx.x * blockDim.x + threadIdx.x;
  if (ch >= Co) return;
  float s = 0.f, q = 0.f;
  for (int i = 0; i < nslots; i++) {
    s += slots[((size_t)ch * NSLOT + i) * 2];
    q += slots[((size_t)ch * NSLOT + i) * 2 + 1];
  }
  float mu = s / (float)BNc;
  float var = q / (float)BNc - mu * mu;
  bnmr[ch * 2] = mu;
  bnmr[ch * 2 + 1] = rsqrtf(var + 1e-5f);
}

// ---------------- bn apply + relu: fp32 pre -> fp16 pb column slice ----------------
__global__ __launch_bounds__(256) void bnapply_kernel(const float* __restrict__ pre,
                                                      int Co, const float* __restrict__ bnmr,
                                                      short* __restrict__ pb, int coff) {
  int gid = blockIdx.x * 256 + threadIdx.x;   // over BN*Co exact
  int row = gid / Co, ch = gid - row * Co;
  float mu = bnmr[ch * 2], rs = bnmr[ch * 2 + 1];
  float v = (pre[gid] - mu) * rs;
  pb[(size_t)row * 512 + coff + ch] = f2h(v > 0.f ? v : 0.f);
}

// ---------------- pooling: partial max/sum via atomics into zeroed g ----------------
__global__ __launch_bounds__(512) void g2_kernel(const short* __restrict__ pre,
                                                 const float* __restrict__ bnmr,
                                                 float* __restrict__ g) {
  int b = blockIdx.x, nch = blockIdx.y;
  int tid = threadIdx.x;            // 0..511 -> channels 2*tid, 2*tid+1
  int ch0 = 2 * tid;
  float mu0 = bnmr[ch0 * 2],     rs0 = bnmr[ch0 * 2 + 1];
  float mu1 = bnmr[ch0 * 2 + 2], rs1 = bnmr[ch0 * 2 + 3];
  const uint32_t* p32 = (const uint32_t*)(pre + (size_t)b * 1024 * 1024 + (size_t)nch * 128 * 1024);
  float mx0 = 0.f, mx1 = 0.f, sm0 = 0.f, sm1 = 0.f;
#pragma unroll 4
  for (int n = 0; n < 128; n++) {
    uint32_t u = p32[n * 512 + tid];
    float v0 = (h2f((short)(u & 0xffff)) - mu0) * rs0;
    float v1 = (h2f((short)(u >> 16))    - mu1) * rs1;
    v0 = v0 > 0.f ? v0 : 0.f;
    v1 = v1 > 0.f ? v1 : 0.f;
    mx0 = fmaxf(mx0, v0); mx1 = fmaxf(mx1, v1);
    sm0 += v0; sm1 += v1;
  }
  int* gi = (int*)g;
  atomicMax(&gi[b * 2048 + ch0], __float_as_int(mx0));
  atomicMax(&gi[b * 2048 + ch0 + 1], __float_as_int(mx1));
  atomicAdd(&g[b * 2048 + 1024 + ch0], sm0 * (1.f / 1024.f));
  atomicAdd(&g[b * 2048 + 1024 + ch0 + 1], sm1 * (1.f / 1024.f));
}

// ---------------- head: split-K linear with atomic reduce ----------------
__global__ __launch_bounds__(256) void linsplit_kernel(const float* __restrict__ A,
                                                       const float* __restrict__ W,
                                                       float* __restrict__ out,
                                                       int Kdim, int Cols, int kchunk) {
  int j = blockIdx.x * 256 + threadIdx.x;
  if (j >= Cols) return;
  int b = blockIdx.y;
  int k0 = blockIdx.z * kchunk;
  const float* a = A + (size_t)b * Kdim + k0;
  const float* w = W + (size_t)k0 * Cols + j;
  float acc = 0.f;
#pragma unroll 4
  for (int i = 0; i < kchunk; i++) acc += a[i] * w[(size_t)i * Cols];
  atomicAdd(&out[b * Cols + j], acc);
}

__global__ __launch_bounds__(256) void biasinit_kernel(const float* __restrict__ bias,
                                                       float* __restrict__ out, int Cols, int n) {
  int gid = blockIdx.x * 256 + threadIdx.x;
  if (gid < n) out[gid] = bias[gid % Cols];
}

__global__ __launch_bounds__(256) void lin_bn_kernel(float* __restrict__ X, int Cols) {
  int j = blockIdx.x * 256 + threadIdx.x;
  if (j >= Cols) return;
  float s = 0.f, q = 0.f;
#pragma unroll
  for (int b = 0; b < 32; b++) { float v = X[b * Cols + j]; s += v; q += v * v; }
  float mu = s * (1.f / 32.f);
  float var = q * (1.f / 32.f) - mu * mu;
  float rs = rsqrtf(var + 1e-5f);
#pragma unroll
  for (int b = 0; b < 32; b++) {
    float v = (X[b * Cols + j] - mu) * rs;
    X[b * Cols + j] = v > 0.f ? v : 0.f;
  }
}

// ---------------- launcher ----------------
extern "C" void kernel_launch(void* const* d_in, const int* in_sizes, int n_in,
                              void* d_out, int out_size, void* d_ws, size_t ws_size,
                              hipStream_t stream) {
  (void)in_sizes; (void)n_in; (void)out_size; (void)ws_size;
  const float* x      = (const float*)d_in[0];
  const float* mat1   = (const float*)d_in[1];
  const float* sn1_w1 = (const float*)d_in[2];
  const float* sn1_w2 = (const float*)d_in[3];
  const float* sn1_b  = (const float*)d_in[4];
  const float* mat2   = (const float*)d_in[5];
  const float* sn2_w1 = (const float*)d_in[6];
  const float* sn2_w2 = (const float*)d_in[7];
  const float* sn2_b  = (const float*)d_in[8];
  const float* mat3   = (const float*)d_in[9];
  const float* sn3_w1 = (const float*)d_in[10];
  const float* sn3_w2 = (const float*)d_in[11];
  const float* sn3_b  = (const float*)d_in[12];
  const float* mat4   = (const float*)d_in[13];
  const float* sn4_w1 = (const float*)d_in[14];
  const float* sn4_w2 = (const float*)d_in[15];
  const float* sn4_b  = (const float*)d_in[16];
  const float* conv5w = (const float*)d_in[17];
  const float* lin1w  = (const float*)d_in[18];
  const float* lin2w  = (const float*)d_in[19];
  const float* lin3w  = (const float*)d_in[20];
  const float* lin3b  = (const float*)d_in[21];
  float* out = (float*)d_out;

  char* ws = (char*)d_ws;
  size_t cur = 0;
  auto alloc = [&](size_t bytes) {
    size_t r = cur;
    cur += (bytes + 1023) & ~(size_t)1023;
    return r;
  };
  size_t off_idx   = alloc((size_t)BNKc * 4);            // 2.62 MB
  size_t off_xT    = alloc((size_t)BNc * 3 * 4);         // 0.39 MB
  size_t off_st    = alloc((size_t)1200000 * 4);         // 4.8 MB (stats + bnslots)
  size_t off_sum   = alloc((size_t)BNc * 8 * 2);         // 0.52 MB
  size_t off_score = alloc((size_t)BNKc * 8 * 4);        // 20.97 MB
  size_t off_pre   = alloc((size_t)BNc * 256 * 4);       // 33.55 MB fp32 pre1..4
  size_t off_pb    = alloc((size_t)BNc * 512 * 2);       // 33.55 MB fp16
  size_t off_kb    = alloc((size_t)1048576);             // 1.05 MB fp16
  size_t off_TU    = alloc((size_t)BNc * 1024 * 2);      // 67.11 MB fp16 (T / pre5 overlay)

  int*   idx   = (int*)(ws + off_idx);
  float* xT    = (float*)(ws + off_xT);
  float* stats = (float*)(ws + off_st);
  short* sumb  = (short*)(ws + off_sum);
  float* score = (float*)(ws + off_score);
  float* pre   = (float*)(ws + off_pre);
  short* pb    = (short*)(ws + off_pb);
  short* kb    = (short*)(ws + off_kb);
  short* T     = (short*)(ws + off_TU);
  short* pre5  = (short*)(ws + off_TU);   // overlays T (dead after L4)

  float* xyzacc  = stats;                 // 64
  float* snstats = stats + 64;            // 128
  float* bnslots = stats + 192;           // 1024*NSLOT*2 = 1,048,576
  float* bnmr    = stats + 1048768;       // 2048
  float* g       = stats + 1050816;       // 65536
  float* h1      = stats + 1116352;       // 16384
  float* h2      = stats + 1132736;       // 8192

  zero_kernel<<<1, 64, 0, stream>>>(xyzacc, 64);
  knn_kernel<<<BNc / 4, 256, 0, stream>>>(x, idx);
  xt_kernel<<<BNc * 3 / 256, 256, 0, stream>>>(x, xT);
  xyz_stats_kernel<<<320, 256, 0, stream>>>(xT, idx, xyzacc);
  snstats_kernel<<<1, 64, 0, stream>>>(xyzacc, sn1_w1, sn2_w1, sn3_w1, sn4_w1, snstats);

  // ---- layer 1 (C=3 -> Co=64), fused fp32 path ----
  score_kernel<<<BNKc / 256, 256, 0, stream>>>(xT, idx, sn1_w1, sn1_w2, sn1_b, snstats + 0, score);
  paconv_kernel<3, 64, 8><<<BNc / 8, 256, 0, stream>>>(xT, 3, mat1, score, idx, pre, 64);
  bnstats_kernel<false><<<dim3(1, 32), 256, 0, stream>>>(pre, 64, bnslots);
  bnfinalize_kernel<<<1, 64, 0, stream>>>(bnslots, bnmr, 64, 32);
  bnapply_kernel<<<BNc * 64 / 256, 256, 0, stream>>>(pre, 64, bnmr, pb, 0);

  // ---- layer 2 (64 -> 64), rank-1 gemm w/ fused stats, KH=512 ----
  score_kernel<<<BNKc / 256, 256, 0, stream>>>(xT, idx, sn2_w1, sn2_w2, sn2_b, snstats + 32, score);
  gather_kernel<64><<<BNc / 4, 256, 0, stream>>>(pb, 0, score, idx, T, sumb);
  kerconv_r1_kernel<<<64 * 1024 / 256, 256, 0, stream>>>(mat2, kb, 64, 64, 64 * 1024);
  gemm_r1_kernel<64, 64, 64><<<dim3(512, 1), 256, 0, stream>>>(T, kb, pb, 0, sumb, pre, 64, bnslots);
  bnfinalize_kernel<<<1, 64, 0, stream>>>(bnslots, bnmr, 64, 512);
  bnapply_kernel<<<BNc * 64 / 256, 256, 0, stream>>>(pre, 64, bnmr, pb, 64);

  // ---- layer 3 (64 -> 128), rank-1 gemm w/ fused stats, KH=512 ----
  score_kernel<<<BNKc / 256, 256, 0, stream>>>(xT, idx, sn3_w1, sn3_w2, sn3_b, snstats + 64, score);
  gather_kernel<64><<<BNc / 4, 256, 0, stream>>>(pb, 64, score, idx, T, sumb);
  kerconv_r1_kernel<<<128 * 1024 / 256, 256, 0, stream>>>(mat3, kb, 64, 128, 128 * 1024);
  gemm_r1_kernel<64, 128, 64><<<dim3(512, 1), 256, 0, stream>>>(T, kb, pb, 64, sumb, pre, 128, bnslots);
  bnfinalize_kernel<<<1, 128, 0, stream>>>(bnslots, bnmr, 128, 512);
  bnapply_kernel<<<BNc * 128 / 256, 256, 0, stream>>>(pre, 128, bnmr, pb, 128);

  // ---- layer 4 (128 -> 256), rank-1 gemm w/ fused stats, KH=1024 ----
  score_kernel<<<BNKc / 256, 256, 0, stream>>>(xT, idx, sn4_w1, sn4_w2, sn4_b, snstats + 96, score);
  gather_kernel<128><<<BNc / 2, 256, 0, stream>>>(pb, 128, score, idx, T, sumb);
  kerconv_r1_kernel<<<256 * 2048 / 256, 256, 0, stream>>>(mat4, kb, 128, 256, 256 * 2048);
  gemm_r1_kernel<64, 128, 128><<<dim3(512, 2), 256, 0, stream>>>(T, kb, pb, 128, sumb, pre, 256, bnslots);
  bnfinalize_kernel<<<1, 256, 0, stream>>>(bnslots, bnmr, 256, 512);
  bnapply_kernel<<<BNc * 256 / 256, 256, 0, stream>>>(pre, 256, bnmr, pb, 256);

  // ---- conv5: (32768x512)x(512x1024), BM=128 fp16 MFMA w/ fused stats ----
  w5conv_kernel<<<524288 / 256, 256, 0, stream>>>(conv5w, kb);
  gemm_kernel<128, 128, true><<<dim3(256, 8), 256, 0, stream>>>(pb, kb, 512, pre5, 1024, bnslots);
  bnfinalize_kernel<<<4, 256, 0, stream>>>(bnslots, bnmr, 1024, 256);

  // ---- pooling (atomic partials into zeroed g) ----
  zero_kernel<<<256, 256, 0, stream>>>(g, 65536);
  g2_kernel<<<dim3(32, 8), 512, 0, stream>>>(pre5, bnmr, g);

  // ---- head (fp32, split-K atomic) ----
  zero_kernel<<<64, 256, 0, stream>>>(h1, 16384);
  linsplit_kernel<<<dim3(2, 32, 8), 256, 0, stream>>>(g, lin1w, h1, 2048, 512, 256);
  lin_bn_kernel<<<2, 256, 0, stream>>>(h1, 512);
  zero_kernel<<<32, 256, 0, stream>>>(h2, 8192);
  linsplit_kernel<<<dim3(1, 32, 4), 256, 0, stream>>>(h1, lin2w, h2, 512, 256, 128);
  lin_bn_kernel<<<1, 256, 0, stream>>>(h2, 256);
  biasinit_kernel<<<5, 256, 0, stream>>>(lin3b, out, 40, 1280);
  linsplit_kernel<<<dim3(1, 32, 2), 256, 0, stream>>>(h2, lin3w, out, 256, 40, 128);
}

// Round 15
// 813.700 us; speedup vs baseline: 1.2041x; 1.2041x over previous
//
#include <hip/hip_runtime.h>
#include <cstdint>
#include <cstddef>

static constexpr int Bc  = 32;
static constexpr int Nc  = 1024;
static constexpr int Kc  = 20;
static constexpr int Mc  = 8;
static constexpr int BNc = Bc * Nc;          // 32768
static constexpr int BNKc = BNc * Kc;        // 655360

typedef __attribute__((ext_vector_type(4))) float f32x4;
typedef _Float16 f16x8 __attribute__((ext_vector_type(8)));

__device__ inline short f2h(float v) { _Float16 h = (_Float16)v; return __builtin_bit_cast(short, h); }
__device__ inline float h2f(short s) { return (float)__builtin_bit_cast(_Float16, s); }

// ---------------- zero kernel ----------------
__global__ void zero_kernel(float* p, int n) {
  int gid = blockIdx.x * blockDim.x + threadIdx.x;
  if (gid < n) p[gid] = 0.f;
}

// ---------------- KNN: register-resident selection, 4 waves/block, 1 point/wave ----------------
__global__ __launch_bounds__(256) void knn_kernel(const float* __restrict__ x,
                                                  int* __restrict__ idxout) {
  int wv = threadIdx.x >> 6;
  int bn = blockIdx.x * 4 + wv;
  int b = bn >> 10, n = bn & (Nc - 1);
  int lane = threadIdx.x & 63;
  const float* xb = x + (size_t)b * 3 * Nc;
  float cx = xb[n], cy = xb[Nc + n], cz = xb[2 * Nc + n];
  float sqc = cx * cx + cy * cy + cz * cz;
  float d[16];
#pragma unroll
  for (int j = 0; j < 16; j++) {
    int m2 = j * 64 + lane;
    float xm = xb[m2], ym = xb[Nc + m2], zm = xb[2 * Nc + m2];
    d[j] = 2.f * (cx * xm + cy * ym + cz * zm) - sqc - (xm * xm + ym * ym + zm * zm);
  }
  int* out = idxout + (size_t)bn * Kc;
  for (int kk = 0; kk < Kc; kk++) {
    float bd = d[0]; int bj = 0;
#pragma unroll
    for (int j = 1; j < 16; j++)
      if (d[j] > bd) { bd = d[j]; bj = j; }
    int bm = bj * 64 + lane;
#pragma unroll
    for (int off = 32; off; off >>= 1) {
      float od = __shfl_down(bd, off);
      int   om = __shfl_down(bm, off);
      if (od > bd || (od == bd && om < bm)) { bd = od; bm = om; }
    }
    bm = __shfl(bm, 0);
    if (lane == 0) out[kk] = bm;
    int bmj = bm >> 6;
    bool mine = (bm & 63) == lane;
#pragma unroll
    for (int j = 0; j < 16; j++)
      if (mine && j == bmj) d[j] = -3e38f;
  }
}

// ---------------- x transpose: (B,3,N) -> (B,N,3) ----------------
__global__ __launch_bounds__(256) void xt_kernel(const float* __restrict__ x,
                                                 float* __restrict__ xT) {
  int gid = blockIdx.x * blockDim.x + threadIdx.x;   // over B*N*3
  int c = gid % 3;
  int bn = gid / 3;
  int b = bn >> 10, n = bn & (Nc - 1);
  xT[gid] = x[((size_t)b * 3 + c) * Nc + n];
}

// xyz recompute helper
__device__ inline void xyz_at(const float* __restrict__ xT, const int* __restrict__ idx,
                              int e, float v[6]) {
  int bn = e / Kc;
  int b = bn >> 10;
  int nb = idx[e];
  const float* pc = xT + (size_t)bn * 3;
  const float* pn = xT + ((size_t)(b << 10) + nb) * 3;
#pragma unroll
  for (int c = 0; c < 3; c++) { float nv = pn[c]; v[c] = nv - pc[c]; v[3 + c] = nv; }
}

// ---------------- xyz statistics ----------------
__global__ __launch_bounds__(256) void xyz_stats_kernel(const float* __restrict__ xT,
                                                        const int* __restrict__ idx,
                                                        float* __restrict__ accum) {
  __shared__ float sPart[4 * 42];
  int tid = threadIdx.x;
  int gid = blockIdx.x * 256 + tid;
  float a[42];
#pragma unroll
  for (int t = 0; t < 42; t++) a[t] = 0.f;
  for (int i = 0; i < 8; i++) {
    float v[6];
    xyz_at(xT, idx, gid + i * 81920, v);
#pragma unroll
    for (int c = 0; c < 6; c++) a[c] += v[c];
    int t = 6;
#pragma unroll
    for (int c = 0; c < 6; c++)
#pragma unroll
      for (int d = 0; d < 6; d++) a[t++] += v[c] * v[d];
  }
  int lane = tid & 63, wid = tid >> 6;
#pragma unroll
  for (int t = 0; t < 42; t++) {
    float v = a[t];
#pragma unroll
    for (int off = 32; off; off >>= 1) v += __shfl_down(v, off);
    if (lane == 0) sPart[wid * 42 + t] = v;
  }
  __syncthreads();
  if (tid < 42) {
    float s = sPart[tid] + sPart[42 + tid] + sPart[84 + tid] + sPart[126 + tid];
    atomicAdd(&accum[tid], s);
  }
}

// ---------------- scorenet bn stats (all 4 layers) ----------------
__global__ void snstats_kernel(const float* __restrict__ accum,
                               const float* __restrict__ w1a, const float* __restrict__ w1b,
                               const float* __restrict__ w1c, const float* __restrict__ w1d,
                               float* __restrict__ snstats) {
  int t = threadIdx.x;       // 0..63
  int l = t >> 4, j = t & 15;
  const float* w1 = (l == 0) ? w1a : (l == 1) ? w1b : (l == 2) ? w1c : w1d;
  const float invc = 1.f / (float)BNKc;
  float wj[6];
  float mu = 0.f;
#pragma unroll
  for (int c = 0; c < 6; c++) { wj[c] = w1[c * 16 + j]; mu += accum[c] * invc * wj[c]; }
  float e2 = 0.f;
#pragma unroll
  for (int c = 0; c < 6; c++)
#pragma unroll
    for (int d = 0; d < 6; d++) e2 += wj[c] * wj[d] * (accum[6 + c * 6 + d] * invc);
  float var = e2 - mu * mu;
  snstats[t * 2] = mu;
  snstats[t * 2 + 1] = rsqrtf(var + 1e-5f);
}

// ---------------- score kernel (standalone, fully parallel over BNK) ----------------
__global__ __launch_bounds__(256) void score_kernel(const float* __restrict__ xT,
                                                    const int* __restrict__ idx,
                                                    const float* __restrict__ w1,
                                                    const float* __restrict__ w2,
                                                    const float* __restrict__ bias,
                                                    const float* __restrict__ snst,
                                                    float* __restrict__ score) {
  __shared__ float sW1[96], sW2[128], sB[8], sMu[16], sRs[16];
  int tid = threadIdx.x;
  if (tid < 96) sW1[tid] = w1[tid];
  else if (tid < 224) sW2[tid - 96] = w2[tid - 96];
  else if (tid < 232) sB[tid - 224] = bias[tid - 224];
  else if (tid < 248) { sMu[tid - 232] = snst[(tid - 232) * 2]; sRs[tid - 232] = snst[(tid - 232) * 2 + 1]; }
  __syncthreads();
  int e = blockIdx.x * 256 + tid;    // exact BNK
  float v[6];
  xyz_at(xT, idx, e, v);
  float h[16];
#pragma unroll
  for (int j = 0; j < 16; j++) {
    float a = 0.f;
#pragma unroll
    for (int c = 0; c < 6; c++) a += v[c] * sW1[c * 16 + j];
    a = (a - sMu[j]) * sRs[j];
    h[j] = a > 0.f ? a : 0.f;
  }
  float s[8];
  float mx = -3e38f;
#pragma unroll
  for (int m = 0; m < 8; m++) {
    float a = sB[m];
#pragma unroll
    for (int j = 0; j < 16; j++) a += h[j] * sW2[j * 8 + m];
    s[m] = a;
    mx = fmaxf(mx, a);
  }
  float sum = 0.f;
#pragma unroll
  for (int m = 0; m < 8; m++) { s[m] = expf(s[m] - mx); sum += s[m]; }
  float inv = 1.f / sum;
#pragma unroll
  for (int m = 0; m < 8; m++) score[(size_t)e * 8 + m] = s[m] * inv + 0.5f;
}

// ---------------- L1 fused paconv (fp32 compute, fp32 out, no atomics) ----------------
template <int C, int Co, int MH>
__global__ __launch_bounds__(256) void paconv_kernel(
    const float* __restrict__ feat, int fstride,
    const float* __restrict__ ker,
    const float* __restrict__ score,
    const int* __restrict__ idx,
    float* __restrict__ outp, int ostride) {
  constexpr int PT = 8;
  constexpr int MS = Mc / MH;
  __shared__ float sX[PT][2 * MH * C];
  __shared__ float sSc[PT * Kc * Mc];
  __shared__ int sIdx[PT * Kc];
  __shared__ float sFc[PT][C];
  __shared__ float sSum[PT][Mc];

  int tid = threadIdx.x;
  int pbase = blockIdx.x * PT;
  int bN = pbase & ~(Nc - 1);

  for (int e = tid; e < PT * Kc; e += 256) sIdx[e] = idx[(size_t)pbase * Kc + e];
  for (int e = tid; e < PT * Kc * Mc; e += 256) sSc[e] = score[(size_t)pbase * Kc * Mc + e];
  for (int e = tid; e < PT * C; e += 256) {
    int p = e / C, c = e - p * C;
    sFc[p][c] = feat[(size_t)(pbase + p) * fstride + c];
  }
  __syncthreads();
  for (int e = tid; e < PT * Mc; e += 256) {
    int p = e >> 3, m = e & 7;
    float s = 0.f;
#pragma unroll
    for (int k = 0; k < Kc; k++) s += sSc[p * Kc * Mc + k * Mc + m];
    sSum[p][m] = s;
  }
  __syncthreads();

  constexpr int OG = Co;
  constexpr int PG = 256 / OG;
  constexpr int PPT = PT / PG;
  int o = tid % OG;
  int pg = tid / OG;
  float acc[PPT];
#pragma unroll
  for (int i = 0; i < PPT; i++) acc[i] = 0.f;

  for (int ms = 0; ms < MS; ms++) {
    int mb = ms * MH;
    for (int e = tid; e < PT * C; e += 256) {
      int p = e / C, c = e - p * C;
      float t[MH];
#pragma unroll
      for (int mm = 0; mm < MH; mm++) t[mm] = 0.f;
      const float* sc = &sSc[p * Kc * Mc + mb];
      for (int k = 0; k < Kc; k++) {
        float v = feat[(size_t)(bN + sIdx[p * Kc + k]) * fstride + c];
#pragma unroll
        for (int mm = 0; mm < MH; mm++) t[mm] += sc[k * Mc + mm] * v;
      }
      float fc = sFc[p][c];
#pragma unroll
      for (int mm = 0; mm < MH; mm++) {
        sX[p][mm * C + c] = t[mm] - sSum[p][mb + mm] * fc;
        sX[p][MH * C + mm * C + c] = t[mm];
      }
    }
    __syncthreads();
#pragma unroll
    for (int mm = 0; mm < MH; mm++) {
      int m = mb + mm;
      const float* kerm = ker + (size_t)m * Co + o;
      for (int c = 0; c < C; c++) {
        float wA = kerm[(size_t)c * (Mc * Co)];
        float wB = kerm[(size_t)(C + c) * (Mc * Co)];
        int r = mm * C + c;
#pragma unroll
        for (int i = 0; i < PPT; i++) {
          int p = pg * PPT + i;
          acc[i] += sX[p][r] * wA;
          acc[i] += sX[p][MH * C + r] * wB;
        }
      }
    }
    __syncthreads();
  }

#pragma unroll
  for (int i = 0; i < PPT; i++) {
    int p = pg * PPT + i;
    outp[(size_t)(pbase + p) * ostride + o] = acc[i];
  }
}

// ---------------- gather: build T (rows x M*C) fp16 + per-point sum (8) fp16 ----------------
template <int C>
__global__ __launch_bounds__(256) void gather_kernel(
    const short* __restrict__ pb, int coff,
    const float* __restrict__ score,
    const int* __restrict__ idx,
    short* __restrict__ T, short* __restrict__ sumb) {
  constexpr int PT = 256 / C;
  constexpr int KH = Mc * C;
  __shared__ float sSc[PT][Kc][Mc];
  __shared__ int   sIdx[PT][Kc];
  int tid = threadIdx.x;
  int pbase = blockIdx.x * PT;
  int bbase = pbase & ~(Nc - 1);
  for (int e = tid; e < PT * Kc * Mc; e += 256) (&sSc[0][0][0])[e] = score[(size_t)pbase * Kc * Mc + e];
  for (int e = tid; e < PT * Kc; e += 256) (&sIdx[0][0])[e] = idx[(size_t)pbase * Kc + e];
  __syncthreads();
  if (tid < PT * Mc) {
    int p = tid >> 3, m = tid & 7;
    float s = 0.f;
#pragma unroll
    for (int k = 0; k < Kc; k++) s += sSc[p][k][m];
    sumb[(size_t)(pbase + p) * 8 + m] = f2h(s);
  }
  int p = tid / C, c = tid - p * C;
  float t[Mc];
#pragma unroll
  for (int m = 0; m < Mc; m++) t[m] = 0.f;
  for (int k = 0; k < Kc; k++) {
    float v = h2f(pb[(size_t)(bbase + sIdx[p][k]) * 512 + coff + c]);
#pragma unroll
    for (int m = 0; m < Mc; m++) t[m] += sSc[p][k][m] * v;
  }
  short* rowp = T + (size_t)(pbase + p) * KH;
#pragma unroll
  for (int m = 0; m < Mc; m++) rowp[m * C + c] = f2h(t[m]);
}

// ---------------- kernel-matrix convert (rank1 form): B' = [Wa+Wb ; -Wa], (Co x 2KH) fp16 ----------------
__global__ __launch_bounds__(256) void kerconv_r1_kernel(const float* __restrict__ ker,
                                                         short* __restrict__ Bt,
                                                         int C, int Co, int total) {
  int gid = blockIdx.x * 256 + threadIdx.x;
  if (gid >= total) return;
  int KH = Mc * C;
  int K2 = 2 * KH;
  int o = gid / K2, r = gid - o * K2;
  float v;
  if (r < KH) {
    int m = r / C, c = r - m * C;
    v = ker[(size_t)c * (Mc * Co) + m * Co + o] + ker[(size_t)(C + c) * (Mc * Co) + m * Co + o];
  } else {
    int r2 = r - KH;
    int m = r2 / C, c = r2 - m * C;
    v = -ker[(size_t)c * (Mc * Co) + m * Co + o];
  }
  Bt[gid] = f2h(v);
}

// conv5 weight convert: W(512,1024) fp32 -> Wt(1024,512) fp16
__global__ __launch_bounds__(256) void w5conv_kernel(const float* __restrict__ W,
                                                     short* __restrict__ Wt) {
  int gid = blockIdx.x * 256 + threadIdx.x;   // 524288 exact
  int o = gid >> 9, k = gid & 511;
  Wt[gid] = f2h(W[(size_t)k * 1024 + o]);
}

// ---------------- plain fp16 MFMA GEMM (used by conv5) ----------------
template <int BM, int BN, bool OUT_HALF>
__global__ __launch_bounds__(256) void gemm_kernel(
    const short* __restrict__ A,
    const short* __restrict__ Bt,
    int K,
    void* __restrict__ Cout, int ldc) {
  constexpr int BK = 64;
  constexpr int FN = BN / 32;
  constexpr int FMW = BM / 32;
  __shared__ short sA[BM * BK];
  __shared__ short sB[BN * BK];
  int tid = threadIdx.x;
  int lane = tid & 63, wv = tid >> 6;
  int wrow = (wv & 1) * (BM / 2);
  int wcol = (wv >> 1) * (BN / 2);
  int bm0 = blockIdx.x * BM;
  int bn0 = blockIdx.y * BN;
  int r15 = lane & 15, quad = lane >> 4;
  int swz = r15 & 7;

  f32x4 acc[FMW][FN];
#pragma unroll
  for (int fm = 0; fm < FMW; fm++)
#pragma unroll
    for (int fn = 0; fn < FN; fn++) acc[fm][fn] = (f32x4){0.f, 0.f, 0.f, 0.f};

  for (int k0 = 0; k0 < K; k0 += BK) {
#pragma unroll
    for (int i = 0; i < (BM * BK / 8) / 256; i++) {
      int cb = i * 256 + wv * 64;
      int chunk = cb + lane;
      int row = chunk >> 3, kc = (chunk & 7) ^ (row & 7);
      const short* g = A + (size_t)(bm0 + row) * K + k0 + kc * 8;
      __builtin_amdgcn_global_load_lds((const __attribute__((address_space(1))) void*)g,
                                       (__attribute__((address_space(3))) void*)&sA[cb * 8],
                                       16, 0, 0);
    }
#pragma unroll
    for (int i = 0; i < (BN * BK / 8) / 256; i++) {
      int cb = i * 256 + wv * 64;
      int chunk = cb + lane;
      int row = chunk >> 3, kc = (chunk & 7) ^ (row & 7);
      const short* g = Bt + (size_t)(bn0 + row) * K + k0 + kc * 8;
      __builtin_amdgcn_global_load_lds((const __attribute__((address_space(1))) void*)g,
                                       (__attribute__((address_space(3))) void*)&sB[cb * 8],
                                       16, 0, 0);
    }
    __syncthreads();
#pragma unroll
    for (int kk = 0; kk < BK; kk += 32) {
      f16x8 af[FMW], bf[FN];
      int ccol = (kk >> 3) + quad;
#pragma unroll
      for (int fm = 0; fm < FMW; fm++)
        af[fm] = *(const f16x8*)&sA[(wrow + fm * 16 + r15) * BK + ((ccol ^ swz) * 8)];
#pragma unroll
      for (int fn = 0; fn < FN; fn++)
        bf[fn] = *(const f16x8*)&sB[(wcol + fn * 16 + r15) * BK + ((ccol ^ swz) * 8)];
#pragma unroll
      for (int fm = 0; fm < FMW; fm++)
#pragma unroll
        for (int fn = 0; fn < FN; fn++)
          acc[fm][fn] = __builtin_amdgcn_mfma_f32_16x16x32_f16(af[fm], bf[fn], acc[fm][fn], 0, 0, 0);
    }
    __syncthreads();
  }

#pragma unroll
  for (int fn = 0; fn < FN; fn++) {
    int col = bn0 + wcol + fn * 16 + r15;
#pragma unroll
    for (int fm = 0; fm < FMW; fm++) {
      int rowb = bm0 + wrow + fm * 16 + quad * 4;
#pragma unroll
      for (int r = 0; r < 4; r++) {
        float v = acc[fm][fn][r];
        if constexpr (OUT_HALF) ((short*)Cout)[(size_t)(rowb + r) * ldc + col] = f2h(v);
        else                    ((float*)Cout)[(size_t)(rowb + r) * ldc + col] = v;
      }
    }
  }
}

// ---------------- rank-1 fp16 MFMA GEMM (L2/L3/L4), fp16 output ----------------
// out = T*(Wa+Wb) - (sum (x) fc)*Wa ; A k>=KH computed in-LDS from sum*fc.
template <int BM, int BN, int C>
__global__ __launch_bounds__(256) void gemm_r1_kernel(
    const short* __restrict__ T,
    const short* __restrict__ Bt,
    const short* __restrict__ pb, int coff,
    const short* __restrict__ sumb,
    short* __restrict__ Cout, int ldc) {
  constexpr int BK = 64;
  constexpr int KH = Mc * C;
  constexpr int K2 = 2 * KH;
  constexpr int FN = BN / 32;
  constexpr int FMW = BM / 32;
  __shared__ short sA[BM * BK];
  __shared__ short sB[BN * BK];
  __shared__ short sFc[BM * C];
  __shared__ short sSm[BM * 8];
  int tid = threadIdx.x;
  int lane = tid & 63, wv = tid >> 6;
  int wrow = (wv & 1) * (BM / 2);
  int wcol = (wv >> 1) * (BN / 2);
  int bm0 = blockIdx.x * BM;
  int bn0 = blockIdx.y * BN;
  int r15 = lane & 15, quad = lane >> 4;
  int swz = r15 & 7;

  for (int e = tid; e < BM * C; e += 256) {
    int p = e / C, c = e - p * C;
    sFc[e] = pb[(size_t)(bm0 + p) * 512 + coff + c];
  }
  for (int e = tid; e < BM * 8; e += 256) sSm[e] = sumb[(size_t)bm0 * 8 + e];

  f32x4 acc[FMW][FN];
#pragma unroll
  for (int fm = 0; fm < FMW; fm++)
#pragma unroll
    for (int fn = 0; fn < FN; fn++) acc[fm][fn] = (f32x4){0.f, 0.f, 0.f, 0.f};
  __syncthreads();

  for (int k0 = 0; k0 < K2; k0 += BK) {
    if (k0 < KH) {
#pragma unroll
      for (int i = 0; i < (BM * BK / 8) / 256; i++) {
        int cb = i * 256 + wv * 64;
        int chunk = cb + lane;
        int row = chunk >> 3, kc = (chunk & 7) ^ (row & 7);
        const short* g = T + (size_t)(bm0 + row) * KH + k0 + kc * 8;
        __builtin_amdgcn_global_load_lds((const __attribute__((address_space(1))) void*)g,
                                         (__attribute__((address_space(3))) void*)&sA[cb * 8],
                                         16, 0, 0);
      }
    } else {
#pragma unroll
      for (int i = 0; i < (BM * BK / 8) / 256; i++) {
        int cb = i * 256 + wv * 64;
        int chunk = cb + lane;
        int row = chunk >> 3, kc = (chunk & 7) ^ (row & 7);
        int kb = (k0 - KH) + kc * 8;
        int m = kb / C, c = kb - m * C;      // constexpr C -> shifts
        _Float16 sm = __builtin_bit_cast(_Float16, sSm[row * 8 + m]);
        f16x8 fcv = *(const f16x8*)&sFc[row * C + c];
        f16x8 val;
#pragma unroll
        for (int j = 0; j < 8; j++) val[j] = sm * fcv[j];
        *(f16x8*)&sA[chunk * 8] = val;
      }
    }
#pragma unroll
    for (int i = 0; i < (BN * BK / 8) / 256; i++) {
      int cb = i * 256 + wv * 64;
      int chunk = cb + lane;
      int row = chunk >> 3, kc = (chunk & 7) ^ (row & 7);
      const short* g = Bt + (size_t)(bn0 + row) * K2 + k0 + kc * 8;
      __builtin_amdgcn_global_load_lds((const __attribute__((address_space(1))) void*)g,
                                       (__attribute__((address_space(3))) void*)&sB[cb * 8],
                                       16, 0, 0);
    }
    __syncthreads();
#pragma unroll
    for (int kk = 0; kk < BK; kk += 32) {
      f16x8 af[FMW], bf[FN];
      int ccol = (kk >> 3) + quad;
#pragma unroll
      for (int fm = 0; fm < FMW; fm++)
        af[fm] = *(const f16x8*)&sA[(wrow + fm * 16 + r15) * BK + ((ccol ^ swz) * 8)];
#pragma unroll
      for (int fn = 0; fn < FN; fn++)
        bf[fn] = *(const f16x8*)&sB[(wcol + fn * 16 + r15) * BK + ((ccol ^ swz) * 8)];
#pragma unroll
      for (int fm = 0; fm < FMW; fm++)
#pragma unroll
        for (int fn = 0; fn < FN; fn++)
          acc[fm][fn] = __builtin_amdgcn_mfma_f32_16x16x32_f16(af[fm], bf[fn], acc[fm][fn], 0, 0, 0);
    }
    __syncthreads();
  }

#pragma unroll
  for (int fn = 0; fn < FN; fn++) {
    int col = bn0 + wcol + fn * 16 + r15;
#pragma unroll
    for (int fm = 0; fm < FMW; fm++) {
      int rowb = bm0 + wrow + fm * 16 + quad * 4;
#pragma unroll
      for (int r = 0; r < 4; r++)
        Cout[(size_t)(rowb + r) * ldc + col] = f2h(acc[fm][fn][r]);
    }
  }
}

// ---------------- bn stats reduction: pre (32768 x Co) -> bnslots[(ch*32+slot)*2] ----------------
template <bool IS_HALF>
__global__ __launch_bounds__(256) void bnstats_kernel(const void* __restrict__ pre,
                                                      int Co,
                                                      float* __restrict__ bnslots) {
  __shared__ float sS[4][64], sQ[4][64];
  int tid = threadIdx.x;
  int c = tid & 63, tg = tid >> 6;
  int ch = blockIdx.x * 64 + c;
  int row0 = blockIdx.y * 1024 + tg * 256;
  float s = 0.f, q = 0.f;
  if constexpr (IS_HALF) {
    const short* p = (const short*)pre + (size_t)row0 * Co + ch;
#pragma unroll 4
    for (int r = 0; r < 256; r++) {
      float v = h2f(p[(size_t)r * Co]);
      s += v; q += v * v;
    }
  } else {
    const float* p = (const float*)pre + (size_t)row0 * Co + ch;
#pragma unroll 4
    for (int r = 0; r < 256; r++) {
      float v = p[(size_t)r * Co];
      s += v; q += v * v;
    }
  }
  sS[tg][c] = s; sQ[tg][c] = q;
  __syncthreads();
  if (tid < 64) {
    float ts = sS[0][tid] + sS[1][tid] + sS[2][tid] + sS[3][tid];
    float tq = sQ[0][tid] + sQ[1][tid] + sQ[2][tid] + sQ[3][tid];
    int chh = blockIdx.x * 64 + tid;
    bnslots[(chh * 32 + blockIdx.y) * 2 + 0] = ts;
    bnslots[(chh * 32 + blockIdx.y) * 2 + 1] = tq;
  }
}

// ---------------- bn finalize ----------------
__global__ void bnfinalize_kernel(const float* __restrict__ slots,
                                  float* __restrict__ bnmr, int Co) {
  int ch = blockIdx.x * blockDim.x + threadIdx.x;
  if (ch >= Co) return;
  float s = 0.f, q = 0.f;
#pragma unroll 4
  for (int i = 0; i < 32; i++) { s += slots[(ch * 32 + i) * 2]; q += slots[(ch * 32 + i) * 2 + 1]; }
  float mu = s / (float)BNc;
  float var = q / (float)BNc - mu * mu;
  bnmr[ch * 2] = mu;
  bnmr[ch * 2 + 1] = rsqrtf(var + 1e-5f);
}

// ---------------- bn apply + relu: fp32 pre -> fp16 pb column slice (L1) ----------------
__global__ __launch_bounds__(256) void bnapply_kernel(const float* __restrict__ pre,
                                                      int Co, const float* __restrict__ bnmr,
                                                      short* __restrict__ pb, int coff) {
  int gid = blockIdx.x * 256 + threadIdx.x;   // over BN*Co exact
  int row = gid / Co, ch = gid - row * Co;
  float mu = bnmr[ch * 2], rs = bnmr[ch * 2 + 1];
  float v = (pre[gid] - mu) * rs;
  pb[(size_t)row * 512 + coff + ch] = f2h(v > 0.f ? v : 0.f);
}

// ---------------- bn apply + relu: fp16 pre -> fp16 pb column slice (L2-4) ----------------
__global__ __launch_bounds__(256) void bnapply16_kernel(const short* __restrict__ pre,
                                                        int Co, const float* __restrict__ bnmr,
                                                        short* __restrict__ pb, int coff) {
  int gid = blockIdx.x * 256 + threadIdx.x;   // over BN*Co exact
  int row = gid / Co, ch = gid - row * Co;
  float mu = bnmr[ch * 2], rs = bnmr[ch * 2 + 1];
  float v = (h2f(pre[gid]) - mu) * rs;
  pb[(size_t)row * 512 + coff + ch] = f2h(v > 0.f ? v : 0.f);
}

// ---------------- pooling: partial max/sum via atomics into zeroed g ----------------
__global__ __launch_bounds__(512) void g2_kernel(const short* __restrict__ pre,
                                                 const float* __restrict__ bnmr,
                                                 float* __restrict__ g) {
  int b = blockIdx.x, nch = blockIdx.y;
  int tid = threadIdx.x;            // 0..511 -> channels 2*tid, 2*tid+1
  int ch0 = 2 * tid;
  float mu0 = bnmr[ch0 * 2],     rs0 = bnmr[ch0 * 2 + 1];
  float mu1 = bnmr[ch0 * 2 + 2], rs1 = bnmr[ch0 * 2 + 3];
  const uint32_t* p32 = (const uint32_t*)(pre + (size_t)b * 1024 * 1024 + (size_t)nch * 128 * 1024);
  float mx0 = 0.f, mx1 = 0.f, sm0 = 0.f, sm1 = 0.f;
#pragma unroll 4
  for (int n = 0; n < 128; n++) {
    uint32_t u = p32[n * 512 + tid];
    float v0 = (h2f((short)(u & 0xffff)) - mu0) * rs0;
    float v1 = (h2f((short)(u >> 16))    - mu1) * rs1;
    v0 = v0 > 0.f ? v0 : 0.f;
    v1 = v1 > 0.f ? v1 : 0.f;
    mx0 = fmaxf(mx0, v0); mx1 = fmaxf(mx1, v1);
    sm0 += v0; sm1 += v1;
  }
  int* gi = (int*)g;
  atomicMax(&gi[b * 2048 + ch0], __float_as_int(mx0));
  atomicMax(&gi[b * 2048 + ch0 + 1], __float_as_int(mx1));
  atomicAdd(&g[b * 2048 + 1024 + ch0], sm0 * (1.f / 1024.f));
  atomicAdd(&g[b * 2048 + 1024 + ch0 + 1], sm1 * (1.f / 1024.f));
}

// ---------------- head: split-K linear with atomic reduce ----------------
__global__ __launch_bounds__(256) void linsplit_kernel(const float* __restrict__ A,
                                                       const float* __restrict__ W,
                                                       float* __restrict__ out,
                                                       int Kdim, int Cols, int kchunk) {
  int j = blockIdx.x * 256 + threadIdx.x;
  if (j >= Cols) return;
  int b = blockIdx.y;
  int k0 = blockIdx.z * kchunk;
  const float* a = A + (size_t)b * Kdim + k0;
  const float* w = W + (size_t)k0 * Cols + j;
  float acc = 0.f;
#pragma unroll 4
  for (int i = 0; i < kchunk; i++) acc += a[i] * w[(size_t)i * Cols];
  atomicAdd(&out[b * Cols + j], acc);
}

__global__ __launch_bounds__(256) void biasinit_kernel(const float* __restrict__ bias,
                                                       float* __restrict__ out, int Cols, int n) {
  int gid = blockIdx.x * 256 + threadIdx.x;
  if (gid < n) out[gid] = bias[gid % Cols];
}

__global__ __launch_bounds__(256) void lin_bn_kernel(float* __restrict__ X, int Cols) {
  int j = blockIdx.x * 256 + threadIdx.x;
  if (j >= Cols) return;
  float s = 0.f, q = 0.f;
#pragma unroll
  for (int b = 0; b < 32; b++) { float v = X[b * Cols + j]; s += v; q += v * v; }
  float mu = s * (1.f / 32.f);
  float var = q * (1.f / 32.f) - mu * mu;
  float rs = rsqrtf(var + 1e-5f);
#pragma unroll
  for (int b = 0; b < 32; b++) {
    float v = (X[b * Cols + j] - mu) * rs;
    X[b * Cols + j] = v > 0.f ? v : 0.f;
  }
}

// ---------------- launcher ----------------
extern "C" void kernel_launch(void* const* d_in, const int* in_sizes, int n_in,
                              void* d_out, int out_size, void* d_ws, size_t ws_size,
                              hipStream_t stream) {
  (void)in_sizes; (void)n_in; (void)out_size; (void)ws_size;
  const float* x      = (const float*)d_in[0];
  const float* mat1   = (const float*)d_in[1];
  const float* sn1_w1 = (const float*)d_in[2];
  const float* sn1_w2 = (const float*)d_in[3];
  const float* sn1_b  = (const float*)d_in[4];
  const float* mat2   = (const float*)d_in[5];
  const float* sn2_w1 = (const float*)d_in[6];
  const float* sn2_w2 = (const float*)d_in[7];
  const float* sn2_b  = (const float*)d_in[8];
  const float* mat3   = (const float*)d_in[9];
  const float* sn3_w1 = (const float*)d_in[10];
  const float* sn3_w2 = (const float*)d_in[11];
  const float* sn3_b  = (const float*)d_in[12];
  const float* mat4   = (const float*)d_in[13];
  const float* sn4_w1 = (const float*)d_in[14];
  const float* sn4_w2 = (const float*)d_in[15];
  const float* sn4_b  = (const float*)d_in[16];
  const float* conv5w = (const float*)d_in[17];
  const float* lin1w  = (const float*)d_in[18];
  const float* lin2w  = (const float*)d_in[19];
  const float* lin3w  = (const float*)d_in[20];
  const float* lin3b  = (const float*)d_in[21];
  float* out = (float*)d_out;

  char* ws = (char*)d_ws;
  size_t cur = 0;
  auto alloc = [&](size_t bytes) {
    size_t r = cur;
    cur += (bytes + 1023) & ~(size_t)1023;
    return r;
  };
  size_t off_idx   = alloc((size_t)BNKc * 4);            // 2.62 MB
  size_t off_xT    = alloc((size_t)BNc * 3 * 4);         // 0.39 MB
  size_t off_st    = alloc((size_t)157888 * 4);          // 0.63 MB
  size_t off_sum   = alloc((size_t)BNc * 8 * 2);         // 0.52 MB
  size_t off_score = alloc((size_t)BNKc * 8 * 4);        // 20.97 MB
  size_t off_pre   = alloc((size_t)BNc * 256 * 4);       // 33.55 MB (fp32 L1 pre / fp16 L2-4 pre)
  size_t off_pb    = alloc((size_t)BNc * 512 * 2);       // 33.55 MB fp16
  size_t off_kb    = alloc((size_t)1048576);             // 1.05 MB fp16
  size_t off_TU    = alloc((size_t)BNc * 1024 * 2);      // 67.11 MB fp16 (T / pre5 overlay)

  int*   idx   = (int*)(ws + off_idx);
  float* xT    = (float*)(ws + off_xT);
  float* stats = (float*)(ws + off_st);
  short* sumb  = (short*)(ws + off_sum);
  float* score = (float*)(ws + off_score);
  float* pre   = (float*)(ws + off_pre);
  short* pre16 = (short*)(ws + off_pre);
  short* pb    = (short*)(ws + off_pb);
  short* kb    = (short*)(ws + off_kb);
  short* T     = (short*)(ws + off_TU);
  short* pre5  = (short*)(ws + off_TU);   // overlays T (dead after L4)

  float* xyzacc  = stats;           // 64
  float* snstats = stats + 64;      // 128
  float* bnslots = stats + 192;     // 65536
  float* bnmr    = stats + 65728;   // 2048
  float* g       = stats + 67776;   // 65536
  float* h1      = stats + 133312;  // 16384
  float* h2      = stats + 149696;  // 8192

  zero_kernel<<<1, 64, 0, stream>>>(xyzacc, 64);
  knn_kernel<<<BNc / 4, 256, 0, stream>>>(x, idx);
  xt_kernel<<<BNc * 3 / 256, 256, 0, stream>>>(x, xT);
  xyz_stats_kernel<<<320, 256, 0, stream>>>(xT, idx, xyzacc);
  snstats_kernel<<<1, 64, 0, stream>>>(xyzacc, sn1_w1, sn2_w1, sn3_w1, sn4_w1, snstats);

  // ---- layer 1 (C=3 -> Co=64), fused fp32 path ----
  score_kernel<<<BNKc / 256, 256, 0, stream>>>(xT, idx, sn1_w1, sn1_w2, sn1_b, snstats + 0, score);
  paconv_kernel<3, 64, 8><<<BNc / 8, 256, 0, stream>>>(xT, 3, mat1, score, idx, pre, 64);
  bnstats_kernel<false><<<dim3(1, 32), 256, 0, stream>>>(pre, 64, bnslots);
  bnfinalize_kernel<<<1, 64, 0, stream>>>(bnslots, bnmr, 64);
  bnapply_kernel<<<BNc * 64 / 256, 256, 0, stream>>>(pre, 64, bnmr, pb, 0);

  // ---- layer 2 (64 -> 64), rank-1 gemm, fp16 pre, KH=512 ----
  score_kernel<<<BNKc / 256, 256, 0, stream>>>(xT, idx, sn2_w1, sn2_w2, sn2_b, snstats + 32, score);
  gather_kernel<64><<<BNc / 4, 256, 0, stream>>>(pb, 0, score, idx, T, sumb);
  kerconv_r1_kernel<<<64 * 1024 / 256, 256, 0, stream>>>(mat2, kb, 64, 64, 64 * 1024);
  gemm_r1_kernel<64, 64, 64><<<dim3(512, 1), 256, 0, stream>>>(T, kb, pb, 0, sumb, pre16, 64);
  bnstats_kernel<true><<<dim3(1, 32), 256, 0, stream>>>(pre16, 64, bnslots);
  bnfinalize_kernel<<<1, 64, 0, stream>>>(bnslots, bnmr, 64);
  bnapply16_kernel<<<BNc * 64 / 256, 256, 0, stream>>>(pre16, 64, bnmr, pb, 64);

  // ---- layer 3 (64 -> 128), rank-1 gemm, fp16 pre, KH=512 ----
  score_kernel<<<BNKc / 256, 256, 0, stream>>>(xT, idx, sn3_w1, sn3_w2, sn3_b, snstats + 64, score);
  gather_kernel<64><<<BNc / 4, 256, 0, stream>>>(pb, 64, score, idx, T, sumb);
  kerconv_r1_kernel<<<128 * 1024 / 256, 256, 0, stream>>>(mat3, kb, 64, 128, 128 * 1024);
  gemm_r1_kernel<64, 128, 64><<<dim3(512, 1), 256, 0, stream>>>(T, kb, pb, 64, sumb, pre16, 128);
  bnstats_kernel<true><<<dim3(2, 32), 256, 0, stream>>>(pre16, 128, bnslots);
  bnfinalize_kernel<<<1, 128, 0, stream>>>(bnslots, bnmr, 128);
  bnapply16_kernel<<<BNc * 128 / 256, 256, 0, stream>>>(pre16, 128, bnmr, pb, 128);

  // ---- layer 4 (128 -> 256), rank-1 gemm, fp16 pre, KH=1024 ----
  score_kernel<<<BNKc / 256, 256, 0, stream>>>(xT, idx, sn4_w1, sn4_w2, sn4_b, snstats + 96, score);
  gather_kernel<128><<<BNc / 2, 256, 0, stream>>>(pb, 128, score, idx, T, sumb);
  kerconv_r1_kernel<<<256 * 2048 / 256, 256, 0, stream>>>(mat4, kb, 128, 256, 256 * 2048);
  gemm_r1_kernel<64, 128, 128><<<dim3(512, 2), 256, 0, stream>>>(T, kb, pb, 128, sumb, pre16, 256);
  bnstats_kernel<true><<<dim3(4, 32), 256, 0, stream>>>(pre16, 256, bnslots);
  bnfinalize_kernel<<<1, 256, 0, stream>>>(bnslots, bnmr, 256);
  bnapply16_kernel<<<BNc * 256 / 256, 256, 0, stream>>>(pre16, 256, bnmr, pb, 256);

  // ---- conv5: (32768x512)x(512x1024), BM=128 fp16 MFMA, out fp16 pre5 ----
  w5conv_kernel<<<524288 / 256, 256, 0, stream>>>(conv5w, kb);
  gemm_kernel<128, 128, true><<<dim3(256, 8), 256, 0, stream>>>(pb, kb, 512, pre5, 1024);
  bnstats_kernel<true><<<dim3(16, 32), 256, 0, stream>>>(pre5, 1024, bnslots);
  bnfinalize_kernel<<<4, 256, 0, stream>>>(bnslots, bnmr, 1024);

  // ---- pooling (atomic partials into zeroed g) ----
  zero_kernel<<<256, 256, 0, stream>>>(g, 65536);
  g2_kernel<<<dim3(32, 8), 512, 0, stream>>>(pre5, bnmr, g);

  // ---- head (fp32, split-K atomic) ----
  zero_kernel<<<64, 256, 0, stream>>>(h1, 16384);
  linsplit_kernel<<<dim3(2, 32, 8), 256, 0, stream>>>(g, lin1w, h1, 2048, 512, 256);
  lin_bn_kernel<<<2, 256, 0, stream>>>(h1, 512);
  zero_kernel<<<32, 256, 0, stream>>>(h2, 8192);
  linsplit_kernel<<<dim3(1, 32, 4), 256, 0, stream>>>(h1, lin2w, h2, 512, 256, 128);
  lin_bn_kernel<<<1, 256, 0, stream>>>(h2, 256);
  biasinit_kernel<<<5, 256, 0, stream>>>(lin3b, out, 40, 1280);
  linsplit_kernel<<<dim3(1, 32, 2), 256, 0, stream>>>(h2, lin3w, out, 256, 40, 128);
}

// Round 16
// 780.395 us; speedup vs baseline: 1.2555x; 1.0427x over previous
//
#include <hip/hip_runtime.h>
#include <cstdint>
#include <cstddef>

static constexpr int Bc  = 32;
static constexpr int Nc  = 1024;
static constexpr int Kc  = 20;
static constexpr int Mc  = 8;
static constexpr int BNc = Bc * Nc;          // 32768
static constexpr int BNKc = BNc * Kc;        // 655360

typedef __attribute__((ext_vector_type(4))) float f32x4;
typedef _Float16 f16x8 __attribute__((ext_vector_type(8)));

__device__ inline short f2h(float v) { _Float16 h = (_Float16)v; return __builtin_bit_cast(short, h); }
__device__ inline float h2f(short s) { return (float)__builtin_bit_cast(_Float16, s); }

// ---------------- zero kernel ----------------
__global__ void zero_kernel(float* p, int n) {
  int gid = blockIdx.x * blockDim.x + threadIdx.x;
  if (gid < n) p[gid] = 0.f;
}

// ---------------- KNN: register-resident selection, 4 waves/block, 1 point/wave ----------------
__global__ __launch_bounds__(256) void knn_kernel(const float* __restrict__ x,
                                                  int* __restrict__ idxout) {
  int wv = threadIdx.x >> 6;
  int bn = blockIdx.x * 4 + wv;
  int b = bn >> 10, n = bn & (Nc - 1);
  int lane = threadIdx.x & 63;
  const float* xb = x + (size_t)b * 3 * Nc;
  float cx = xb[n], cy = xb[Nc + n], cz = xb[2 * Nc + n];
  float sqc = cx * cx + cy * cy + cz * cz;
  float d[16];
#pragma unroll
  for (int j = 0; j < 16; j++) {
    int m2 = j * 64 + lane;
    float xm = xb[m2], ym = xb[Nc + m2], zm = xb[2 * Nc + m2];
    d[j] = 2.f * (cx * xm + cy * ym + cz * zm) - sqc - (xm * xm + ym * ym + zm * zm);
  }
  int* out = idxout + (size_t)bn * Kc;
  for (int kk = 0; kk < Kc; kk++) {
    float bd = d[0]; int bj = 0;
#pragma unroll
    for (int j = 1; j < 16; j++)
      if (d[j] > bd) { bd = d[j]; bj = j; }
    int bm = bj * 64 + lane;
#pragma unroll
    for (int off = 32; off; off >>= 1) {
      float od = __shfl_down(bd, off);
      int   om = __shfl_down(bm, off);
      if (od > bd || (od == bd && om < bm)) { bd = od; bm = om; }
    }
    bm = __shfl(bm, 0);
    if (lane == 0) out[kk] = bm;
    int bmj = bm >> 6;
    bool mine = (bm & 63) == lane;
#pragma unroll
    for (int j = 0; j < 16; j++)
      if (mine && j == bmj) d[j] = -3e38f;
  }
}

// ---------------- x transpose: (B,3,N) -> (B,N,3) ----------------
__global__ __launch_bounds__(256) void xt_kernel(const float* __restrict__ x,
                                                 float* __restrict__ xT) {
  int gid = blockIdx.x * blockDim.x + threadIdx.x;   // over B*N*3
  int c = gid % 3;
  int bn = gid / 3;
  int b = bn >> 10, n = bn & (Nc - 1);
  xT[gid] = x[((size_t)b * 3 + c) * Nc + n];
}

// xyz recompute helper
__device__ inline void xyz_at(const float* __restrict__ xT, const int* __restrict__ idx,
                              int e, float v[6]) {
  int bn = e / Kc;
  int b = bn >> 10;
  int nb = idx[e];
  const float* pc = xT + (size_t)bn * 3;
  const float* pn = xT + ((size_t)(b << 10) + nb) * 3;
#pragma unroll
  for (int c = 0; c < 3; c++) { float nv = pn[c]; v[c] = nv - pc[c]; v[3 + c] = nv; }
}

// ---------------- xyz statistics ----------------
__global__ __launch_bounds__(256) void xyz_stats_kernel(const float* __restrict__ xT,
                                                        const int* __restrict__ idx,
                                                        float* __restrict__ accum) {
  __shared__ float sPart[4 * 42];
  int tid = threadIdx.x;
  int gid = blockIdx.x * 256 + tid;
  float a[42];
#pragma unroll
  for (int t = 0; t < 42; t++) a[t] = 0.f;
  for (int i = 0; i < 8; i++) {
    float v[6];
    xyz_at(xT, idx, gid + i * 81920, v);
#pragma unroll
    for (int c = 0; c < 6; c++) a[c] += v[c];
    int t = 6;
#pragma unroll
    for (int c = 0; c < 6; c++)
#pragma unroll
      for (int d = 0; d < 6; d++) a[t++] += v[c] * v[d];
  }
  int lane = tid & 63, wid = tid >> 6;
#pragma unroll
  for (int t = 0; t < 42; t++) {
    float v = a[t];
#pragma unroll
    for (int off = 32; off; off >>= 1) v += __shfl_down(v, off);
    if (lane == 0) sPart[wid * 42 + t] = v;
  }
  __syncthreads();
  if (tid < 42) {
    float s = sPart[tid] + sPart[42 + tid] + sPart[84 + tid] + sPart[126 + tid];
    atomicAdd(&accum[tid], s);
  }
}

// ---------------- scorenet bn stats (all 4 layers) ----------------
__global__ void snstats_kernel(const float* __restrict__ accum,
                               const float* __restrict__ w1a, const float* __restrict__ w1b,
                               const float* __restrict__ w1c, const float* __restrict__ w1d,
                               float* __restrict__ snstats) {
  int t = threadIdx.x;       // 0..63
  int l = t >> 4, j = t & 15;
  const float* w1 = (l == 0) ? w1a : (l == 1) ? w1b : (l == 2) ? w1c : w1d;
  const float invc = 1.f / (float)BNKc;
  float wj[6];
  float mu = 0.f;
#pragma unroll
  for (int c = 0; c < 6; c++) { wj[c] = w1[c * 16 + j]; mu += accum[c] * invc * wj[c]; }
  float e2 = 0.f;
#pragma unroll
  for (int c = 0; c < 6; c++)
#pragma unroll
    for (int d = 0; d < 6; d++) e2 += wj[c] * wj[d] * (accum[6 + c * 6 + d] * invc);
  float var = e2 - mu * mu;
  snstats[t * 2] = mu;
  snstats[t * 2 + 1] = rsqrtf(var + 1e-5f);
}

// ---------------- score4: all 4 layers' scores in one pass, fp16 out ----------------
__global__ __launch_bounds__(256) void score4_kernel(
    const float* __restrict__ xT, const int* __restrict__ idx,
    const float* __restrict__ w1a, const float* __restrict__ w2a, const float* __restrict__ b1,
    const float* __restrict__ w1b, const float* __restrict__ w2b, const float* __restrict__ b2,
    const float* __restrict__ w1c, const float* __restrict__ w2c, const float* __restrict__ b3,
    const float* __restrict__ w1d, const float* __restrict__ w2d, const float* __restrict__ b4,
    const float* __restrict__ snst, short* __restrict__ score4) {
  __shared__ float sW1[4][96], sW2[4][128], sB[4][8], sMu[4][16], sRs[4][16];
  int tid = threadIdx.x;
  if (tid < 96) { sW1[0][tid] = w1a[tid]; sW1[1][tid] = w1b[tid]; sW1[2][tid] = w1c[tid]; sW1[3][tid] = w1d[tid]; }
  else if (tid < 224) { int t = tid - 96; sW2[0][t] = w2a[t]; sW2[1][t] = w2b[t]; sW2[2][t] = w2c[t]; sW2[3][t] = w2d[t]; }
  else if (tid < 232) { int t = tid - 224; sB[0][t] = b1[t]; sB[1][t] = b2[t]; sB[2][t] = b3[t]; sB[3][t] = b4[t]; }
  else if (tid < 248) {
    int t = tid - 232;
#pragma unroll
    for (int l = 0; l < 4; l++) { sMu[l][t] = snst[(l * 16 + t) * 2]; sRs[l][t] = snst[(l * 16 + t) * 2 + 1]; }
  }
  __syncthreads();
  int e = blockIdx.x * 256 + tid;    // exact BNK
  float v[6];
  xyz_at(xT, idx, e, v);
#pragma unroll
  for (int l = 0; l < 4; l++) {
    float h[16];
#pragma unroll
    for (int j = 0; j < 16; j++) {
      float a = 0.f;
#pragma unroll
      for (int c = 0; c < 6; c++) a += v[c] * sW1[l][c * 16 + j];
      a = (a - sMu[l][j]) * sRs[l][j];
      h[j] = a > 0.f ? a : 0.f;
    }
    float s[8];
    float mx = -3e38f;
#pragma unroll
    for (int m = 0; m < 8; m++) {
      float a = sB[l][m];
#pragma unroll
      for (int j = 0; j < 16; j++) a += h[j] * sW2[l][j * 8 + m];
      s[m] = a;
      mx = fmaxf(mx, a);
    }
    float sum = 0.f;
#pragma unroll
    for (int m = 0; m < 8; m++) { s[m] = expf(s[m] - mx); sum += s[m]; }
    float inv = 1.f / sum;
    short* op = score4 + (size_t)l * BNKc * 8 + (size_t)e * 8;
#pragma unroll
    for (int m = 0; m < 8; m++) op[m] = f2h(s[m] * inv + 0.5f);
  }
}

// ---------------- L1 fused paconv (fp32 compute, fp32 out; fp16 score in) ----------------
template <int C, int Co, int MH>
__global__ __launch_bounds__(256) void paconv_kernel(
    const float* __restrict__ feat, int fstride,
    const float* __restrict__ ker,
    const short* __restrict__ score,
    const int* __restrict__ idx,
    float* __restrict__ outp, int ostride) {
  constexpr int PT = 8;
  constexpr int MS = Mc / MH;
  __shared__ float sX[PT][2 * MH * C];
  __shared__ float sSc[PT * Kc * Mc];
  __shared__ int sIdx[PT * Kc];
  __shared__ float sFc[PT][C];
  __shared__ float sSum[PT][Mc];

  int tid = threadIdx.x;
  int pbase = blockIdx.x * PT;
  int bN = pbase & ~(Nc - 1);

  for (int e = tid; e < PT * Kc; e += 256) sIdx[e] = idx[(size_t)pbase * Kc + e];
  for (int e = tid; e < PT * Kc * Mc; e += 256) sSc[e] = h2f(score[(size_t)pbase * Kc * Mc + e]);
  for (int e = tid; e < PT * C; e += 256) {
    int p = e / C, c = e - p * C;
    sFc[p][c] = feat[(size_t)(pbase + p) * fstride + c];
  }
  __syncthreads();
  for (int e = tid; e < PT * Mc; e += 256) {
    int p = e >> 3, m = e & 7;
    float s = 0.f;
#pragma unroll
    for (int k = 0; k < Kc; k++) s += sSc[p * Kc * Mc + k * Mc + m];
    sSum[p][m] = s;
  }
  __syncthreads();

  constexpr int OG = Co;
  constexpr int PG = 256 / OG;
  constexpr int PPT = PT / PG;
  int o = tid % OG;
  int pg = tid / OG;
  float acc[PPT];
#pragma unroll
  for (int i = 0; i < PPT; i++) acc[i] = 0.f;

  for (int ms = 0; ms < MS; ms++) {
    int mb = ms * MH;
    for (int e = tid; e < PT * C; e += 256) {
      int p = e / C, c = e - p * C;
      float t[MH];
#pragma unroll
      for (int mm = 0; mm < MH; mm++) t[mm] = 0.f;
      const float* sc = &sSc[p * Kc * Mc + mb];
      for (int k = 0; k < Kc; k++) {
        float v = feat[(size_t)(bN + sIdx[p * Kc + k]) * fstride + c];
#pragma unroll
        for (int mm = 0; mm < MH; mm++) t[mm] += sc[k * Mc + mm] * v;
      }
      float fc = sFc[p][c];
#pragma unroll
      for (int mm = 0; mm < MH; mm++) {
        sX[p][mm * C + c] = t[mm] - sSum[p][mb + mm] * fc;
        sX[p][MH * C + mm * C + c] = t[mm];
      }
    }
    __syncthreads();
#pragma unroll
    for (int mm = 0; mm < MH; mm++) {
      int m = mb + mm;
      const float* kerm = ker + (size_t)m * Co + o;
      for (int c = 0; c < C; c++) {
        float wA = kerm[(size_t)c * (Mc * Co)];
        float wB = kerm[(size_t)(C + c) * (Mc * Co)];
        int r = mm * C + c;
#pragma unroll
        for (int i = 0; i < PPT; i++) {
          int p = pg * PPT + i;
          acc[i] += sX[p][r] * wA;
          acc[i] += sX[p][MH * C + r] * wB;
        }
      }
    }
    __syncthreads();
  }

#pragma unroll
  for (int i = 0; i < PPT; i++) {
    int p = pg * PPT + i;
    outp[(size_t)(pbase + p) * ostride + o] = acc[i];
  }
}

// ---------------- gather: build T (rows x M*C) fp16 + per-point sum (8) fp16; fp16 score in ----------------
template <int C>
__global__ __launch_bounds__(256) void gather_kernel(
    const short* __restrict__ pb, int coff,
    const short* __restrict__ score,
    const int* __restrict__ idx,
    short* __restrict__ T, short* __restrict__ sumb) {
  constexpr int PT = 256 / C;
  constexpr int KH = Mc * C;
  __shared__ float sSc[PT][Kc][Mc];
  __shared__ int   sIdx[PT][Kc];
  int tid = threadIdx.x;
  int pbase = blockIdx.x * PT;
  int bbase = pbase & ~(Nc - 1);
  for (int e = tid; e < PT * Kc * Mc; e += 256) (&sSc[0][0][0])[e] = h2f(score[(size_t)pbase * Kc * Mc + e]);
  for (int e = tid; e < PT * Kc; e += 256) (&sIdx[0][0])[e] = idx[(size_t)pbase * Kc + e];
  __syncthreads();
  if (tid < PT * Mc) {
    int p = tid >> 3, m = tid & 7;
    float s = 0.f;
#pragma unroll
    for (int k = 0; k < Kc; k++) s += sSc[p][k][m];
    sumb[(size_t)(pbase + p) * 8 + m] = f2h(s);
  }
  int p = tid / C, c = tid - p * C;
  float t[Mc];
#pragma unroll
  for (int m = 0; m < Mc; m++) t[m] = 0.f;
  for (int k = 0; k < Kc; k++) {
    float v = h2f(pb[(size_t)(bbase + sIdx[p][k]) * 512 + coff + c]);
#pragma unroll
    for (int m = 0; m < Mc; m++) t[m] += sSc[p][k][m] * v;
  }
  short* rowp = T + (size_t)(pbase + p) * KH;
#pragma unroll
  for (int m = 0; m < Mc; m++) rowp[m * C + c] = f2h(t[m]);
}

// ---------------- all weight conversions in one launch ----------------
// [0,65536): L2 r1 (C=64,Co=64) -> kb+0
// [65536,196608): L3 r1 (C=64,Co=128) -> kb+65536
// [196608,720896): L4 r1 (C=128,Co=256) -> kb+196608
// [720896,1245184): conv5 W(512,1024)->Wt(1024,512) -> kb+720896
__global__ __launch_bounds__(256) void kerconv_all_kernel(
    const float* __restrict__ m2, const float* __restrict__ m3,
    const float* __restrict__ m4, const float* __restrict__ w5,
    short* __restrict__ kb) {
  int gid = blockIdx.x * 256 + threadIdx.x;
  const float* ker; short* dst; int C, Co, g;
  if (gid < 65536)       { ker = m2; dst = kb;          C = 64;  Co = 64;  g = gid; }
  else if (gid < 196608) { ker = m3; dst = kb + 65536;  C = 64;  Co = 128; g = gid - 65536; }
  else if (gid < 720896) { ker = m4; dst = kb + 196608; C = 128; Co = 256; g = gid - 196608; }
  else {
    int g5 = gid - 720896;
    int o = g5 >> 9, k = g5 & 511;
    kb[720896 + g5] = f2h(w5[(size_t)k * 1024 + o]);
    return;
  }
  int KH = Mc * C, K2 = 2 * KH;
  int o = g / K2, r = g - o * K2;
  float v;
  if (r < KH) {
    int m = r / C, c = r - m * C;
    v = ker[(size_t)c * (Mc * Co) + m * Co + o] + ker[(size_t)(C + c) * (Mc * Co) + m * Co + o];
  } else {
    int r2 = r - KH;
    int m = r2 / C, c = r2 - m * C;
    v = -ker[(size_t)c * (Mc * Co) + m * Co + o];
  }
  dst[g] = f2h(v);
}

// ---------------- plain fp16 MFMA GEMM (used by conv5) ----------------
template <int BM, int BN, bool OUT_HALF>
__global__ __launch_bounds__(256) void gemm_kernel(
    const short* __restrict__ A,
    const short* __restrict__ Bt,
    int K,
    void* __restrict__ Cout, int ldc) {
  constexpr int BK = 64;
  constexpr int FN = BN / 32;
  constexpr int FMW = BM / 32;
  __shared__ short sA[BM * BK];
  __shared__ short sB[BN * BK];
  int tid = threadIdx.x;
  int lane = tid & 63, wv = tid >> 6;
  int wrow = (wv & 1) * (BM / 2);
  int wcol = (wv >> 1) * (BN / 2);
  int bm0 = blockIdx.x * BM;
  int bn0 = blockIdx.y * BN;
  int r15 = lane & 15, quad = lane >> 4;
  int swz = r15 & 7;

  f32x4 acc[FMW][FN];
#pragma unroll
  for (int fm = 0; fm < FMW; fm++)
#pragma unroll
    for (int fn = 0; fn < FN; fn++) acc[fm][fn] = (f32x4){0.f, 0.f, 0.f, 0.f};

  for (int k0 = 0; k0 < K; k0 += BK) {
#pragma unroll
    for (int i = 0; i < (BM * BK / 8) / 256; i++) {
      int cb = i * 256 + wv * 64;
      int chunk = cb + lane;
      int row = chunk >> 3, kc = (chunk & 7) ^ (row & 7);
      const short* g = A + (size_t)(bm0 + row) * K + k0 + kc * 8;
      __builtin_amdgcn_global_load_lds((const __attribute__((address_space(1))) void*)g,
                                       (__attribute__((address_space(3))) void*)&sA[cb * 8],
                                       16, 0, 0);
    }
#pragma unroll
    for (int i = 0; i < (BN * BK / 8) / 256; i++) {
      int cb = i * 256 + wv * 64;
      int chunk = cb + lane;
      int row = chunk >> 3, kc = (chunk & 7) ^ (row & 7);
      const short* g = Bt + (size_t)(bn0 + row) * K + k0 + kc * 8;
      __builtin_amdgcn_global_load_lds((const __attribute__((address_space(1))) void*)g,
                                       (__attribute__((address_space(3))) void*)&sB[cb * 8],
                                       16, 0, 0);
    }
    __syncthreads();
#pragma unroll
    for (int kk = 0; kk < BK; kk += 32) {
      f16x8 af[FMW], bf[FN];
      int ccol = (kk >> 3) + quad;
#pragma unroll
      for (int fm = 0; fm < FMW; fm++)
        af[fm] = *(const f16x8*)&sA[(wrow + fm * 16 + r15) * BK + ((ccol ^ swz) * 8)];
#pragma unroll
      for (int fn = 0; fn < FN; fn++)
        bf[fn] = *(const f16x8*)&sB[(wcol + fn * 16 + r15) * BK + ((ccol ^ swz) * 8)];
#pragma unroll
      for (int fm = 0; fm < FMW; fm++)
#pragma unroll
        for (int fn = 0; fn < FN; fn++)
          acc[fm][fn] = __builtin_amdgcn_mfma_f32_16x16x32_f16(af[fm], bf[fn], acc[fm][fn], 0, 0, 0);
    }
    __syncthreads();
  }

#pragma unroll
  for (int fn = 0; fn < FN; fn++) {
    int col = bn0 + wcol + fn * 16 + r15;
#pragma unroll
    for (int fm = 0; fm < FMW; fm++) {
      int rowb = bm0 + wrow + fm * 16 + quad * 4;
#pragma unroll
      for (int r = 0; r < 4; r++) {
        float v = acc[fm][fn][r];
        if constexpr (OUT_HALF) ((short*)Cout)[(size_t)(rowb + r) * ldc + col] = f2h(v);
        else                    ((float*)Cout)[(size_t)(rowb + r) * ldc + col] = v;
      }
    }
  }
}

// ---------------- rank-1 fp16 MFMA GEMM (L2/L3/L4), fp16 output ----------------
template <int BM, int BN, int C>
__global__ __launch_bounds__(256) void gemm_r1_kernel(
    const short* __restrict__ T,
    const short* __restrict__ Bt,
    const short* __restrict__ pb, int coff,
    const short* __restrict__ sumb,
    short* __restrict__ Cout, int ldc) {
  constexpr int BK = 64;
  constexpr int KH = Mc * C;
  constexpr int K2 = 2 * KH;
  constexpr int FN = BN / 32;
  constexpr int FMW = BM / 32;
  __shared__ short sA[BM * BK];
  __shared__ short sB[BN * BK];
  __shared__ short sFc[BM * C];
  __shared__ short sSm[BM * 8];
  int tid = threadIdx.x;
  int lane = tid & 63, wv = tid >> 6;
  int wrow = (wv & 1) * (BM / 2);
  int wcol = (wv >> 1) * (BN / 2);
  int bm0 = blockIdx.x * BM;
  int bn0 = blockIdx.y * BN;
  int r15 = lane & 15, quad = lane >> 4;
  int swz = r15 & 7;

  for (int e = tid; e < BM * C; e += 256) {
    int p = e / C, c = e - p * C;
    sFc[e] = pb[(size_t)(bm0 + p) * 512 + coff + c];
  }
  for (int e = tid; e < BM * 8; e += 256) sSm[e] = sumb[(size_t)bm0 * 8 + e];

  f32x4 acc[FMW][FN];
#pragma unroll
  for (int fm = 0; fm < FMW; fm++)
#pragma unroll
    for (int fn = 0; fn < FN; fn++) acc[fm][fn] = (f32x4){0.f, 0.f, 0.f, 0.f};
  __syncthreads();

  for (int k0 = 0; k0 < K2; k0 += BK) {
    if (k0 < KH) {
#pragma unroll
      for (int i = 0; i < (BM * BK / 8) / 256; i++) {
        int cb = i * 256 + wv * 64;
        int chunk = cb + lane;
        int row = chunk >> 3, kc = (chunk & 7) ^ (row & 7);
        const short* g = T + (size_t)(bm0 + row) * KH + k0 + kc * 8;
        __builtin_amdgcn_global_load_lds((const __attribute__((address_space(1))) void*)g,
                                         (__attribute__((address_space(3))) void*)&sA[cb * 8],
                                         16, 0, 0);
      }
    } else {
#pragma unroll
      for (int i = 0; i < (BM * BK / 8) / 256; i++) {
        int cb = i * 256 + wv * 64;
        int chunk = cb + lane;
        int row = chunk >> 3, kc = (chunk & 7) ^ (row & 7);
        int kb = (k0 - KH) + kc * 8;
        int m = kb / C, c = kb - m * C;      // constexpr C -> shifts
        _Float16 sm = __builtin_bit_cast(_Float16, sSm[row * 8 + m]);
        f16x8 fcv = *(const f16x8*)&sFc[row * C + c];
        f16x8 val;
#pragma unroll
        for (int j = 0; j < 8; j++) val[j] = sm * fcv[j];
        *(f16x8*)&sA[chunk * 8] = val;
      }
    }
#pragma unroll
    for (int i = 0; i < (BN * BK / 8) / 256; i++) {
      int cb = i * 256 + wv * 64;
      int chunk = cb + lane;
      int row = chunk >> 3, kc = (chunk & 7) ^ (row & 7);
      const short* g = Bt + (size_t)(bn0 + row) * K2 + k0 + kc * 8;
      __builtin_amdgcn_global_load_lds((const __attribute__((address_space(1))) void*)g,
                                       (__attribute__((address_space(3))) void*)&sB[cb * 8],
                                       16, 0, 0);
    }
    __syncthreads();
#pragma unroll
    for (int kk = 0; kk < BK; kk += 32) {
      f16x8 af[FMW], bf[FN];
      int ccol = (kk >> 3) + quad;
#pragma unroll
      for (int fm = 0; fm < FMW; fm++)
        af[fm] = *(const f16x8*)&sA[(wrow + fm * 16 + r15) * BK + ((ccol ^ swz) * 8)];
#pragma unroll
      for (int fn = 0; fn < FN; fn++)
        bf[fn] = *(const f16x8*)&sB[(wcol + fn * 16 + r15) * BK + ((ccol ^ swz) * 8)];
#pragma unroll
      for (int fm = 0; fm < FMW; fm++)
#pragma unroll
        for (int fn = 0; fn < FN; fn++)
          acc[fm][fn] = __builtin_amdgcn_mfma_f32_16x16x32_f16(af[fm], bf[fn], acc[fm][fn], 0, 0, 0);
    }
    __syncthreads();
  }

#pragma unroll
  for (int fn = 0; fn < FN; fn++) {
    int col = bn0 + wcol + fn * 16 + r15;
#pragma unroll
    for (int fm = 0; fm < FMW; fm++) {
      int rowb = bm0 + wrow + fm * 16 + quad * 4;
#pragma unroll
      for (int r = 0; r < 4; r++)
        Cout[(size_t)(rowb + r) * ldc + col] = f2h(acc[fm][fn][r]);
    }
  }
}

// ---------------- bn stats reduction: pre (32768 x Co) -> bnslots[(ch*32+slot)*2] ----------------
template <bool IS_HALF>
__global__ __launch_bounds__(256) void bnstats_kernel(const void* __restrict__ pre,
                                                      int Co,
                                                      float* __restrict__ bnslots) {
  __shared__ float sS[4][64], sQ[4][64];
  int tid = threadIdx.x;
  int c = tid & 63, tg = tid >> 6;
  int ch = blockIdx.x * 64 + c;
  int row0 = blockIdx.y * 1024 + tg * 256;
  float s = 0.f, q = 0.f;
  if constexpr (IS_HALF) {
    const short* p = (const short*)pre + (size_t)row0 * Co + ch;
#pragma unroll 4
    for (int r = 0; r < 256; r++) {
      float v = h2f(p[(size_t)r * Co]);
      s += v; q += v * v;
    }
  } else {
    const float* p = (const float*)pre + (size_t)row0 * Co + ch;
#pragma unroll 4
    for (int r = 0; r < 256; r++) {
      float v = p[(size_t)r * Co];
      s += v; q += v * v;
    }
  }
  sS[tg][c] = s; sQ[tg][c] = q;
  __syncthreads();
  if (tid < 64) {
    float ts = sS[0][tid] + sS[1][tid] + sS[2][tid] + sS[3][tid];
    float tq = sQ[0][tid] + sQ[1][tid] + sQ[2][tid] + sQ[3][tid];
    int chh = blockIdx.x * 64 + tid;
    bnslots[(chh * 32 + blockIdx.y) * 2 + 0] = ts;
    bnslots[(chh * 32 + blockIdx.y) * 2 + 1] = tq;
  }
}

// ---------------- bn finalize ----------------
__global__ void bnfinalize_kernel(const float* __restrict__ slots,
                                  float* __restrict__ bnmr, int Co) {
  int ch = blockIdx.x * blockDim.x + threadIdx.x;
  if (ch >= Co) return;
  float s = 0.f, q = 0.f;
#pragma unroll 4
  for (int i = 0; i < 32; i++) { s += slots[(ch * 32 + i) * 2]; q += slots[(ch * 32 + i) * 2 + 1]; }
  float mu = s / (float)BNc;
  float var = q / (float)BNc - mu * mu;
  bnmr[ch * 2] = mu;
  bnmr[ch * 2 + 1] = rsqrtf(var + 1e-5f);
}

// ---------------- bn apply + relu: fp32 pre -> fp16 pb column slice (L1) ----------------
__global__ __launch_bounds__(256) void bnapply_kernel(const float* __restrict__ pre,
                                                      int Co, const float* __restrict__ bnmr,
                                                      short* __restrict__ pb, int coff) {
  int gid = blockIdx.x * 256 + threadIdx.x;   // over BN*Co exact
  int row = gid / Co, ch = gid - row * Co;
  float mu = bnmr[ch * 2], rs = bnmr[ch * 2 + 1];
  float v = (pre[gid] - mu) * rs;
  pb[(size_t)row * 512 + coff + ch] = f2h(v > 0.f ? v : 0.f);
}

// ---------------- bn apply + relu: fp16 pre -> fp16 pb column slice (L2-4) ----------------
__global__ __launch_bounds__(256) void bnapply16_kernel(const short* __restrict__ pre,
                                                        int Co, const float* __restrict__ bnmr,
                                                        short* __restrict__ pb, int coff) {
  int gid = blockIdx.x * 256 + threadIdx.x;   // over BN*Co exact
  int row = gid / Co, ch = gid - row * Co;
  float mu = bnmr[ch * 2], rs = bnmr[ch * 2 + 1];
  float v = (h2f(pre[gid]) - mu) * rs;
  pb[(size_t)row * 512 + coff + ch] = f2h(v > 0.f ? v : 0.f);
}

// ---------------- pooling: partial max/sum via atomics into zeroed g ----------------
__global__ __launch_bounds__(512) void g2_kernel(const short* __restrict__ pre,
                                                 const float* __restrict__ bnmr,
                                                 float* __restrict__ g) {
  int b = blockIdx.x, nch = blockIdx.y;
  int tid = threadIdx.x;            // 0..511 -> channels 2*tid, 2*tid+1
  int ch0 = 2 * tid;
  float mu0 = bnmr[ch0 * 2],     rs0 = bnmr[ch0 * 2 + 1];
  float mu1 = bnmr[ch0 * 2 + 2], rs1 = bnmr[ch0 * 2 + 3];
  const uint32_t* p32 = (const uint32_t*)(pre + (size_t)b * 1024 * 1024 + (size_t)nch * 128 * 1024);
  float mx0 = 0.f, mx1 = 0.f, sm0 = 0.f, sm1 = 0.f;
#pragma unroll 4
  for (int n = 0; n < 128; n++) {
    uint32_t u = p32[n * 512 + tid];
    float v0 = (h2f((short)(u & 0xffff)) - mu0) * rs0;
    float v1 = (h2f((short)(u >> 16))    - mu1) * rs1;
    v0 = v0 > 0.f ? v0 : 0.f;
    v1 = v1 > 0.f ? v1 : 0.f;
    mx0 = fmaxf(mx0, v0); mx1 = fmaxf(mx1, v1);
    sm0 += v0; sm1 += v1;
  }
  int* gi = (int*)g;
  atomicMax(&gi[b * 2048 + ch0], __float_as_int(mx0));
  atomicMax(&gi[b * 2048 + ch0 + 1], __float_as_int(mx1));
  atomicAdd(&g[b * 2048 + 1024 + ch0], sm0 * (1.f / 1024.f));
  atomicAdd(&g[b * 2048 + 1024 + ch0 + 1], sm1 * (1.f / 1024.f));
}

// ---------------- head: split-K linear with atomic reduce ----------------
__global__ __launch_bounds__(256) void linsplit_kernel(const float* __restrict__ A,
                                                       const float* __restrict__ W,
                                                       float* __restrict__ out,
                                                       int Kdim, int Cols, int kchunk) {
  int j = blockIdx.x * 256 + threadIdx.x;
  if (j >= Cols) return;
  int b = blockIdx.y;
  int k0 = blockIdx.z * kchunk;
  const float* a = A + (size_t)b * Kdim + k0;
  const float* w = W + (size_t)k0 * Cols + j;
  float acc = 0.f;
#pragma unroll 4
  for (int i = 0; i < kchunk; i++) acc += a[i] * w[(size_t)i * Cols];
  atomicAdd(&out[b * Cols + j], acc);
}

__global__ __launch_bounds__(256) void biasinit_kernel(const float* __restrict__ bias,
                                                       float* __restrict__ out, int Cols, int n) {
  int gid = blockIdx.x * 256 + threadIdx.x;
  if (gid < n) out[gid] = bias[gid % Cols];
}

__global__ __launch_bounds__(256) void lin_bn_kernel(float* __restrict__ X, int Cols) {
  int j = blockIdx.x * 256 + threadIdx.x;
  if (j >= Cols) return;
  float s = 0.f, q = 0.f;
#pragma unroll
  for (int b = 0; b < 32; b++) { float v = X[b * Cols + j]; s += v; q += v * v; }
  float mu = s * (1.f / 32.f);
  float var = q * (1.f / 32.f) - mu * mu;
  float rs = rsqrtf(var + 1e-5f);
#pragma unroll
  for (int b = 0; b < 32; b++) {
    float v = (X[b * Cols + j] - mu) * rs;
    X[b * Cols + j] = v > 0.f ? v : 0.f;
  }
}

// ---------------- launcher ----------------
extern "C" void kernel_launch(void* const* d_in, const int* in_sizes, int n_in,
                              void* d_out, int out_size, void* d_ws, size_t ws_size,
                              hipStream_t stream) {
  (void)in_sizes; (void)n_in; (void)out_size; (void)ws_size;
  const float* x      = (const float*)d_in[0];
  const float* mat1   = (const float*)d_in[1];
  const float* sn1_w1 = (const float*)d_in[2];
  const float* sn1_w2 = (const float*)d_in[3];
  const float* sn1_b  = (const float*)d_in[4];
  const float* mat2   = (const float*)d_in[5];
  const float* sn2_w1 = (const float*)d_in[6];
  const float* sn2_w2 = (const float*)d_in[7];
  const float* sn2_b  = (const float*)d_in[8];
  const float* mat3   = (const float*)d_in[9];
  const float* sn3_w1 = (const float*)d_in[10];
  const float* sn3_w2 = (const float*)d_in[11];
  const float* sn3_b  = (const float*)d_in[12];
  const float* mat4   = (const float*)d_in[13];
  const float* sn4_w1 = (const float*)d_in[14];
  const float* sn4_w2 = (const float*)d_in[15];
  const float* sn4_b  = (const float*)d_in[16];
  const float* conv5w = (const float*)d_in[17];
  const float* lin1w  = (const float*)d_in[18];
  const float* lin2w  = (const float*)d_in[19];
  const float* lin3w  = (const float*)d_in[20];
  const float* lin3b  = (const float*)d_in[21];
  float* out = (float*)d_out;

  char* ws = (char*)d_ws;
  size_t cur = 0;
  auto alloc = [&](size_t bytes) {
    size_t r = cur;
    cur += (bytes + 1023) & ~(size_t)1023;
    return r;
  };
  size_t off_idx   = alloc((size_t)BNKc * 4);            // 2.62 MB
  size_t off_xT    = alloc((size_t)BNc * 3 * 4);         // 0.39 MB
  size_t off_st    = alloc((size_t)157888 * 4);          // 0.63 MB
  size_t off_sum   = alloc((size_t)BNc * 8 * 2);         // 0.52 MB
  size_t off_score = alloc((size_t)BNKc * 8 * 2 * 4);    // 41.94 MB fp16 scores x4 layers
  size_t off_pre   = alloc((size_t)BNc * 256 * 4);       // 33.55 MB (fp32 L1 / fp16 L2-4)
  size_t off_pb    = alloc((size_t)BNc * 512 * 2);       // 33.55 MB fp16
  size_t off_kb    = alloc((size_t)1245184 * 2);         // 2.49 MB fp16 (all weights)
  size_t off_TU    = alloc((size_t)BNc * 1024 * 2);      // 67.11 MB fp16 (T / pre5 overlay)

  int*   idx    = (int*)(ws + off_idx);
  float* xT     = (float*)(ws + off_xT);
  float* stats  = (float*)(ws + off_st);
  short* sumb   = (short*)(ws + off_sum);
  short* score4 = (short*)(ws + off_score);
  float* pre    = (float*)(ws + off_pre);
  short* pre16  = (short*)(ws + off_pre);
  short* pb     = (short*)(ws + off_pb);
  short* kb     = (short*)(ws + off_kb);
  short* T      = (short*)(ws + off_TU);
  short* pre5   = (short*)(ws + off_TU);   // overlays T (dead after L4)

  float* xyzacc  = stats;           // 64
  float* snstats = stats + 64;      // 128
  float* bnslots = stats + 192;     // 65536
  float* bnmr    = stats + 65728;   // 2048
  float* g       = stats + 67776;   // 65536
  float* h1      = stats + 133312;  // 16384
  float* h2      = stats + 149696;  // 8192

  zero_kernel<<<1, 64, 0, stream>>>(xyzacc, 64);
  knn_kernel<<<BNc / 4, 256, 0, stream>>>(x, idx);
  xt_kernel<<<BNc * 3 / 256, 256, 0, stream>>>(x, xT);
  xyz_stats_kernel<<<320, 256, 0, stream>>>(xT, idx, xyzacc);
  snstats_kernel<<<1, 64, 0, stream>>>(xyzacc, sn1_w1, sn2_w1, sn3_w1, sn4_w1, snstats);

  // all scores (4 layers) + all weight conversions up-front
  score4_kernel<<<BNKc / 256, 256, 0, stream>>>(
      xT, idx, sn1_w1, sn1_w2, sn1_b, sn2_w1, sn2_w2, sn2_b,
      sn3_w1, sn3_w2, sn3_b, sn4_w1, sn4_w2, sn4_b, snstats, score4);
  kerconv_all_kernel<<<4864, 256, 0, stream>>>(mat2, mat3, mat4, conv5w, kb);

  short* sc1 = score4;
  short* sc2 = score4 + (size_t)1 * BNKc * 8;
  short* sc3 = score4 + (size_t)2 * BNKc * 8;
  short* sc4 = score4 + (size_t)3 * BNKc * 8;
  short* kbL2 = kb;
  short* kbL3 = kb + 65536;
  short* kbL4 = kb + 196608;
  short* kbW5 = kb + 720896;

  // ---- layer 1 (C=3 -> Co=64), fused fp32 path ----
  paconv_kernel<3, 64, 8><<<BNc / 8, 256, 0, stream>>>(xT, 3, mat1, sc1, idx, pre, 64);
  bnstats_kernel<false><<<dim3(1, 32), 256, 0, stream>>>(pre, 64, bnslots);
  bnfinalize_kernel<<<1, 64, 0, stream>>>(bnslots, bnmr, 64);
  bnapply_kernel<<<BNc * 64 / 256, 256, 0, stream>>>(pre, 64, bnmr, pb, 0);

  // ---- layer 2 (64 -> 64), rank-1 gemm, fp16 pre, KH=512 ----
  gather_kernel<64><<<BNc / 4, 256, 0, stream>>>(pb, 0, sc2, idx, T, sumb);
  gemm_r1_kernel<64, 64, 64><<<dim3(512, 1), 256, 0, stream>>>(T, kbL2, pb, 0, sumb, pre16, 64);
  bnstats_kernel<true><<<dim3(1, 32), 256, 0, stream>>>(pre16, 64, bnslots);
  bnfinalize_kernel<<<1, 64, 0, stream>>>(bnslots, bnmr, 64);
  bnapply16_kernel<<<BNc * 64 / 256, 256, 0, stream>>>(pre16, 64, bnmr, pb, 64);

  // ---- layer 3 (64 -> 128), rank-1 gemm, fp16 pre, KH=512 ----
  gather_kernel<64><<<BNc / 4, 256, 0, stream>>>(pb, 64, sc3, idx, T, sumb);
  gemm_r1_kernel<64, 128, 64><<<dim3(512, 1), 256, 0, stream>>>(T, kbL3, pb, 64, sumb, pre16, 128);
  bnstats_kernel<true><<<dim3(2, 32), 256, 0, stream>>>(pre16, 128, bnslots);
  bnfinalize_kernel<<<1, 128, 0, stream>>>(bnslots, bnmr, 128);
  bnapply16_kernel<<<BNc * 128 / 256, 256, 0, stream>>>(pre16, 128, bnmr, pb, 128);

  // ---- layer 4 (128 -> 256), rank-1 gemm, fp16 pre, KH=1024 ----
  gather_kernel<128><<<BNc / 2, 256, 0, stream>>>(pb, 128, sc4, idx, T, sumb);
  gemm_r1_kernel<64, 128, 128><<<dim3(512, 2), 256, 0, stream>>>(T, kbL4, pb, 128, sumb, pre16, 256);
  bnstats_kernel<true><<<dim3(4, 32), 256, 0, stream>>>(pre16, 256, bnslots);
  bnfinalize_kernel<<<1, 256, 0, stream>>>(bnslots, bnmr, 256);
  bnapply16_kernel<<<BNc * 256 / 256, 256, 0, stream>>>(pre16, 256, bnmr, pb, 256);

  // ---- conv5: (32768x512)x(512x1024), BM=128 fp16 MFMA, out fp16 pre5 ----
  gemm_kernel<128, 128, true><<<dim3(256, 8), 256, 0, stream>>>(pb, kbW5, 512, pre5, 1024);
  bnstats_kernel<true><<<dim3(16, 32), 256, 0, stream>>>(pre5, 1024, bnslots);
  bnfinalize_kernel<<<4, 256, 0, stream>>>(bnslots, bnmr, 1024);

  // ---- pooling (atomic partials into zeroed g) ----
  zero_kernel<<<256, 256, 0, stream>>>(g, 65536);
  g2_kernel<<<dim3(32, 8), 512, 0, stream>>>(pre5, bnmr, g);

  // ---- head (fp32, split-K atomic) ----
  zero_kernel<<<64, 256, 0, stream>>>(h1, 16384);
  linsplit_kernel<<<dim3(2, 32, 8), 256, 0, stream>>>(g, lin1w, h1, 2048, 512, 256);
  lin_bn_kernel<<<2, 256, 0, stream>>>(h1, 512);
  zero_kernel<<<32, 256, 0, stream>>>(h2, 8192);
  linsplit_kernel<<<dim3(1, 32, 4), 256, 0, stream>>>(h1, lin2w, h2, 512, 256, 128);
  lin_bn_kernel<<<1, 256, 0, stream>>>(h2, 256);
  biasinit_kernel<<<5, 256, 0, stream>>>(lin3b, out, 40, 1280);
  linsplit_kernel<<<dim3(1, 32, 2), 256, 0, stream>>>(h2, lin3w, out, 256, 40, 128);
}